// Round 9
// baseline (459.932 us; speedup 1.0000x reference)
//
#include <hip/hip_runtime.h>
#include <hip/hip_bf16.h>
#include <cstddef>
#include <cstdint>

#define IN_DIM 256
#define HID 128
#define OUT_DIM 40

#define CHUNK 4096      // edges per binscatter block (LDS-staged counting sort)
#define BIN_SHIFT 10    // 1024 nodes per bin
#define BIN_SIZE 1024
#define MAXB 128        // >= NBINS+1
#define GSPLIT 8        // blocks per bin for k_deg

typedef __attribute__((ext_vector_type(8))) short short8;
typedef __attribute__((ext_vector_type(4))) float f32x4;
typedef __attribute__((ext_vector_type(2))) float f32x2;

__device__ inline short f2bf(float f) {
    __hip_bfloat16 b = __float2bfloat16(f);   // RNE
    return __builtin_bit_cast(short, b);
}
__device__ inline float bf2f(unsigned short u) {
    unsigned int v = (unsigned int)u << 16;
    return __builtin_bit_cast(float, v);
}
// feature permutation for h1/x1 storage: slot p holds feature (p>>3) + 16*(p&7).
__device__ inline int permf(int p) { return (p >> 3) + 16 * (p & 7); }

// ---------------- merged init: [0,setupBlocks) = W repacks + deg zeroing; rest = binscatter ----------------
// Binscatter: LDS-staged chunk-private counting sort (avoids ~9x partial-line write amplification
// of scattered 4B/2B global stores — measured R5: WRITE_SIZE 113 MB for 12.5 MB payload).
__global__ __launch_bounds__(256) void k_init(const float* __restrict__ W1, const float* __restrict__ W2,
                                              const float* __restrict__ b1, short* __restrict__ Wg,
                                              short* __restrict__ Wg2, float* __restrict__ b1p,
                                              int* __restrict__ deg_in, int* __restrict__ deg_out, int Z,
                                              const int* __restrict__ src, const int* __restrict__ dst,
                                              uint32_t* __restrict__ stD, unsigned short* __restrict__ stS,
                                              int* __restrict__ bboD, int* __restrict__ bboS,
                                              int E, int NBINS, int setupBlocks) {
    __shared__ __align__(16) uint32_t sgD[CHUNK];         // 16 KB
    __shared__ __align__(16) unsigned short sgS[CHUNK];   // 8 KB
    __shared__ int hD[MAXB], hS[MAXB], sd[MAXB];
    int t = threadIdx.x;
    if (blockIdx.x < setupBlocks) {
        int flat = blockIdx.x * 256 + t;
        if (flat < 8192) {                        // W1: fp32 [256][128] -> bf16 fragments [nt][ks][lane][8]
            int k = flat >> 5;
            int n0 = (flat & 31) * 4;
            float4 v = *(const float4*)(W1 + (size_t)k * HID + n0);
            int ks = k >> 5, quad = (k >> 3) & 3, j = k & 7;
            float vv[4] = {v.x, v.y, v.z, v.w};
#pragma unroll
            for (int e = 0; e < 4; ++e) {
                int n = n0 + e;
                int nt = n >> 4;
                int ln = (n & 15) | (quad << 4);
                Wg[(((nt * 8 + ks) * 64) + ln) * 8 + j] = f2bf(vv[e]);
            }
            return;
        }
        flat -= 8192;
        if (flat < 3 * 4 * 64 * 8) {              // W2: fp32 [128][40] -> bf16 B-fragments (pad cols 40->48)
            int f = flat >> 9;
            int ln = (flat >> 3) & 63;
            int j = flat & 7;
            int nt = f >> 2, ks = f & 3;
            int q = ks * 32 + (ln >> 4) * 8 + j;  // x1 slot (permuted feature index)
            int c = nt * 16 + (ln & 15);          // output col
            float v = (c < OUT_DIM) ? W2[(size_t)permf(q) * OUT_DIM + c] : 0.f;
            Wg2[flat] = f2bf(v);
            return;
        }
        flat -= 3 * 4 * 64 * 8;
        if (flat < HID) { b1p[flat] = b1[permf(flat)]; return; }
        flat -= HID;
        if (flat < Z) { *(int4*)(deg_in + flat * 4) = make_int4(0, 0, 0, 0); return; }
        flat -= Z;
        if (flat < Z) { *(int4*)(deg_out + flat * 4) = make_int4(0, 0, 0, 0); }
        return;
    }
    // ---- binscatter ----
    int j = blockIdx.x - setupBlocks;
    int base = j * CHUNK;
    int nE = min(CHUNK, E - base);
    int NB1 = NBINS + 1;
    for (int i = t; i < MAXB; i += 256) { hD[i] = 0; hS[i] = 0; }
    __syncthreads();
    for (int i = t; i < nE; i += 256) {
        atomicAdd(&hD[dst[base + i] >> BIN_SHIFT], 1);
        atomicAdd(&hS[src[base + i] >> BIN_SHIFT], 1);
    }
    __syncthreads();
    // scan D
    if (t < MAXB) sd[t] = hD[t];
    __syncthreads();
    for (int off = 1; off < MAXB; off <<= 1) {
        int x = 0;
        if (t < MAXB && t >= off) x = sd[t - off];
        __syncthreads();
        if (t < MAXB) sd[t] += x;
        __syncthreads();
    }
    if (t < MAXB) {
        int h = hD[t];
        int c = sd[t] - h;
        hD[t] = c;                                  // hD becomes cursor
        if (t < NBINS) bboD[(size_t)j * NB1 + t] = c;
    }
    if (t == NBINS) bboD[(size_t)j * NB1 + NBINS] = nE;
    __syncthreads();
    // scan S
    if (t < MAXB) sd[t] = hS[t];
    __syncthreads();
    for (int off = 1; off < MAXB; off <<= 1) {
        int x = 0;
        if (t < MAXB && t >= off) x = sd[t - off];
        __syncthreads();
        if (t < MAXB) sd[t] += x;
        __syncthreads();
    }
    if (t < MAXB) {
        int h = hS[t];
        int c = sd[t] - h;
        hS[t] = c;                                  // hS becomes cursor
        if (t < NBINS) bboS[(size_t)j * NB1 + t] = c;
    }
    if (t == NBINS) bboS[(size_t)j * NB1 + NBINS] = nE;
    __syncthreads();
    // scatter into LDS staging
    for (int i = t; i < nE; i += 256) {
        int s = src[base + i], d = dst[base + i];
        int pD = atomicAdd(&hD[d >> BIN_SHIFT], 1);
        sgD[pD] = ((uint32_t)(d & (BIN_SIZE - 1)) << 17) | (uint32_t)s;
        int pS = atomicAdd(&hS[s >> BIN_SHIFT], 1);
        sgS[pS] = (unsigned short)(s & (BIN_SIZE - 1));
    }
    __syncthreads();
    // coalesced flush
    int nh = nE >> 1;
    uint2* dD = (uint2*)(stD + base);
    const uint2* sD = (const uint2*)sgD;
    for (int i = t; i < nh; i += 256) dD[i] = sD[i];
    uint32_t* dS = (uint32_t*)(stS + base);
    const uint32_t* sS = (const uint32_t*)sgS;
    for (int i = t; i < nh; i += 256) dS[i] = sS[i];
    if ((nE & 1) && t == 0) { stD[base + nE - 1] = sgD[nE - 1]; stS[base + nE - 1] = sgS[nE - 1]; }
}

// ---------------- merged degree kernel: z==0 dst, z==1 src ----------------
__global__ __launch_bounds__(256) void k_deg(const uint32_t* __restrict__ stD, const int* __restrict__ bboD,
                                             const unsigned short* __restrict__ stS, const int* __restrict__ bboS,
                                             int* __restrict__ deg_in, int* __restrict__ deg_out,
                                             int nchunk, int NBINS) {
    __shared__ int hist[BIN_SIZE];
    int b = blockIdx.x, g = blockIdx.y, t = threadIdx.x;
    int wv = t >> 6, lane = t & 63;
    int NB1 = NBINS + 1;
    for (int i = t; i < BIN_SIZE; i += 256) hist[i] = 0;
    __syncthreads();
    int base = b << BIN_SHIFT;
    if (blockIdx.z == 0) {
        for (int j = g * 4 + wv; j < nchunk; j += GSPLIT * 4) {
            int s = bboD[(size_t)j * NB1 + b], e = bboD[(size_t)j * NB1 + b + 1];
            const uint32_t* seg = stD + (size_t)j * CHUNK;
            for (int i = s + lane; i < e; i += 64)
                atomicAdd(&hist[seg[i] >> 17], 1);
        }
        __syncthreads();
        for (int i = t; i < BIN_SIZE; i += 256) {
            int v = hist[i];
            if (v) atomicAdd(&deg_in[base + i], v);
        }
    } else {
        for (int j = g * 4 + wv; j < nchunk; j += GSPLIT * 4) {
            int s = bboS[(size_t)j * NB1 + b], e = bboS[(size_t)j * NB1 + b + 1];
            const unsigned short* seg = stS + (size_t)j * CHUNK;
            for (int i = s + lane; i < e; i += 64)
                atomicAdd(&hist[seg[i]], 1);
        }
        __syncthreads();
        for (int i = t; i < BIN_SIZE; i += 256) {
            int v = hist[i];
            if (v) atomicAdd(&deg_out[base + i], v);
        }
    }
}

__global__ __launch_bounds__(256) void k_scan1(const int* __restrict__ deg, int* __restrict__ out,
                                               int* __restrict__ bsum, float* __restrict__ rs_in, int n) {
    __shared__ int sd[256];
    int t = threadIdx.x, b = blockIdx.x;
    int base = b * 1024 + t * 4;
    int v0 = 0, v1 = 0, v2 = 0, v3 = 0;
    if (base + 0 < n) v0 = deg[base + 0];
    if (base + 1 < n) v1 = deg[base + 1];
    if (base + 2 < n) v2 = deg[base + 2];
    if (base + 3 < n) v3 = deg[base + 3];
    if (base + 0 < n) rs_in[base + 0] = rsqrtf((float)max(v0, 1));
    if (base + 1 < n) rs_in[base + 1] = rsqrtf((float)max(v1, 1));
    if (base + 2 < n) rs_in[base + 2] = rsqrtf((float)max(v2, 1));
    if (base + 3 < n) rs_in[base + 3] = rsqrtf((float)max(v3, 1));
    int ts = v0 + v1 + v2 + v3;
    sd[t] = ts;
    __syncthreads();
    for (int off = 1; off < 256; off <<= 1) {
        int x = 0;
        if (t >= off) x = sd[t - off];
        __syncthreads();
        sd[t] += x;
        __syncthreads();
    }
    int excl = sd[t] - ts;
    if (base + 0 < n) out[base + 0] = excl;
    if (base + 1 < n) out[base + 1] = excl + v0;
    if (base + 2 < n) out[base + 2] = excl + v0 + v1;
    if (base + 3 < n) out[base + 3] = excl + v0 + v1 + v2;
    if (t == 255) bsum[b] = sd[255];
}

// scan3 with the (tiny) bsum scan done redundantly per block (removes the 1-block scan2 launch).
// Requires NB <= 128 (N <= 131072; here N = 100000 -> NB = 98).
__global__ __launch_bounds__(256) void k_scan3(int* __restrict__ row_ptr, const int* __restrict__ bsum,
                                               const int* __restrict__ deg_out,
                                               float* __restrict__ rs_out, int n, int E, int NB) {
    __shared__ int sb[128];
    int t = threadIdx.x;
    if (t < 128) sb[t] = (t < NB) ? bsum[t] : 0;
    __syncthreads();
    for (int off = 1; off < 128; off <<= 1) {
        int x = 0;
        if (t < 128 && t >= off) x = sb[t - off];
        __syncthreads();
        if (t < 128) sb[t] += x;
        __syncthreads();
    }
    int i = blockIdx.x * 256 + threadIdx.x;
    if (i < n) {
        int blk = i >> 10;
        int add = (blk > 0) ? sb[blk - 1] : 0;     // exclusive prefix of block sums
        row_ptr[i] += add;
        rs_out[i] = rsqrtf((float)max(deg_out[i], 1));
    }
    if (i == 0) row_ptr[n] = E;
}

// ---------------- merged col + GEMM1 (one launch; complementary pipes overlap) ----------------
// [0, NBINS): col scatter — ONE BLOCK PER BIN. Cursor lives in LDS (seeded from row_ptr), so the
// entire 128KB col window of a bin is written by one block on one XCD: its L2 accumulates full
// lines before write-back (R8 measured 105 MB WRITE for ~26 MB payload — 8 (b,g) owners per line
// across XCDs forced partial-sector writebacks). Also kills hsave + global cursor entirely.
// Each wave keeps 4 chunk-segments in flight for latency hiding.
// [NBINS, ...): GEMM1 — LDS-free (R8): lane's MFMA A-fragment = 8 consecutive k of one row,
// loaded straight from global as 2x float4.
__global__ __launch_bounds__(256) void k_colgemm1(const uint32_t* __restrict__ stD, const int* __restrict__ bboD,
                                                  const int* __restrict__ row_ptr, int* __restrict__ col,
                                                  int nchunk, int NBINS,
                                                  const float* __restrict__ A, const short* __restrict__ Wg,
                                                  const float* __restrict__ rs_out, uint32_t* __restrict__ h1f,
                                                  int M) {
    __shared__ int cur[BIN_SIZE];             // per-node cursors (4 KB) — only LDS in this kernel
    int t = threadIdx.x;
    if (blockIdx.x < (unsigned)NBINS) {
        int b = blockIdx.x;
        int wv = t >> 6, lane = t & 63;
        int NB1 = NBINS + 1;
        int base = b << BIN_SHIFT;
        for (int i = t; i < BIN_SIZE; i += 256) {
            int gn = base + i;
            cur[i] = (gn < M) ? row_ptr[gn] : 0;
        }
        __syncthreads();
        for (int jj = wv * 4; jj < nchunk; jj += 16) {
            int s[4], e[4];
            uint32_t v[4];
            bool av[4];
#pragma unroll
            for (int q = 0; q < 4; ++q) {
                int j = jj + q;
                bool jv = j < nchunk;
                s[q] = jv ? bboD[(size_t)j * NB1 + b] : 0;
                e[q] = jv ? bboD[(size_t)j * NB1 + b + 1] : 0;
            }
#pragma unroll
            for (int q = 0; q < 4; ++q) {
                av[q] = s[q] + lane < e[q];
                v[q] = av[q] ? stD[(size_t)(jj + q) * CHUNK + s[q] + lane] : 0u;
            }
#pragma unroll
            for (int q = 0; q < 4; ++q) {
                if (av[q]) {
                    int pos = atomicAdd(&cur[v[q] >> 17], 1);
                    col[pos] = (int)(v[q] & 0x1FFFFu);
                }
            }
            // rare long segments (> 64 edges in one (chunk,bin) cell)
#pragma unroll
            for (int q = 0; q < 4; ++q) {
                for (int i = s[q] + lane + 64; i < e[q]; i += 64) {
                    uint32_t vv = stD[(size_t)(jj + q) * CHUNK + i];
                    int pos = atomicAdd(&cur[vv >> 17], 1);
                    col[pos] = (int)(vv & 0x1FFFFu);
                }
            }
        }
        return;
    }
    // ---- GEMM1 (LDS-free) ----
    int lane = t & 63, wv = t >> 6;
    int block_row = (blockIdx.x - NBINS) * 64;
    int row = block_row + wv * 16 + (lane & 15);
    bool valid = row < M;
    const float* ap = A + (size_t)row * IN_DIM + (lane >> 4) * 8;
    f32x4 acc[8] = {};
#pragma unroll
    for (int ks = 0; ks < 8; ++ks) {
        float4 va = {0.f, 0.f, 0.f, 0.f}, vb = {0.f, 0.f, 0.f, 0.f};
        if (valid) {
            va = *(const float4*)(ap + ks * 32);
            vb = *(const float4*)(ap + ks * 32 + 4);
        }
        short8 a;
        a[0] = f2bf(va.x); a[1] = f2bf(va.y); a[2] = f2bf(va.z); a[3] = f2bf(va.w);
        a[4] = f2bf(vb.x); a[5] = f2bf(vb.y); a[6] = f2bf(vb.z); a[7] = f2bf(vb.w);
#pragma unroll
        for (int nt = 0; nt < 8; ++nt) {
            short8 b = *(const short8*)&Wg[(((nt * 8 + ks) * 64) + lane) * 8];
            acc[nt] = __builtin_amdgcn_mfma_f32_16x16x32_bf16(a, b, acc[nt], 0, 0, 0);
        }
    }
    int quad = lane >> 4, cl = lane & 15;
#pragma unroll
    for (int r = 0; r < 4; ++r) {
        int gr = block_row + wv * 16 + quad * 4 + r;
        if (gr >= M) continue;
        float sc = rs_out[gr];
        int d0 = __builtin_amdgcn_cvt_pk_fp8_f32(acc[0][r] * sc, acc[1][r] * sc, 0, false);
        d0 = __builtin_amdgcn_cvt_pk_fp8_f32(acc[2][r] * sc, acc[3][r] * sc, d0, true);
        int d1 = __builtin_amdgcn_cvt_pk_fp8_f32(acc[4][r] * sc, acc[5][r] * sc, 0, false);
        d1 = __builtin_amdgcn_cvt_pk_fp8_f32(acc[6][r] * sc, acc[7][r] * sc, d1, true);
        uint2 dd = make_uint2((uint32_t)d0, (uint32_t)d1);
        *(uint2*)((char*)h1f + (size_t)gr * 128 + cl * 8) = dd;
    }
}

// ---------------- Fused SpMM1 + ReLU + GEMM2 (R3-proven block version) ----------------
// Block = 256 threads = 4 waves = 4 nodes (one node per wave).
// Gather: 16 lanes/edge x uint2; 16 edges per it-step = 4 independent loads in flight.
// Hot loop is mask-free (full steps) + one masked tail step. Accumulate in f32x2 (v_pk_add_f32).
// x1 rows parked in LDS (bf16, XOR-swizzled); 12 MFMAs -> h2f fp8, rows padded to 64 B.
__global__ __launch_bounds__(256) void k_spmm1f(const char* __restrict__ h1c, const int* __restrict__ rp,
                                                const int* __restrict__ col, const float* __restrict__ rs_in,
                                                const float* __restrict__ rs_out, const float* __restrict__ b1p,
                                                const short* __restrict__ Wg2,
                                                uint32_t* __restrict__ h2f, int N) {
    __shared__ uint32_t x1s[16 * 64];   // 16 rows x 256 B (only rows 0..3 written), 16B-granule XOR swizzle
    __shared__ uint32_t hs2[48];        // column-major fp8 staging: dword cc = bytes for nodes 0..3
    int t = threadIdx.x;
    int wv = t >> 6, lane = t & 63;
    int grp = lane >> 4, ql = lane & 15;
    int w_base = blockIdx.x * 4;
    int w = w_base + wv;

    float4 blo = *(const float4*)&b1p[ql * 8];
    float4 bhi = *(const float4*)&b1p[ql * 8 + 4];

    if (w < N) {
        int s = rp[w], e = rp[w + 1];
        f32x2 a0 = {0.f, 0.f}, a1 = {0.f, 0.f}, a2 = {0.f, 0.f}, a3 = {0.f, 0.f};
        int qoff = ql << 3;
        int i = s;
        while (i < e) {
            int cnt = min(64, e - i);
            int cl = (lane < cnt) ? lane : cnt - 1;
            int rof = col[i + cl] << 7;          // byte offset of 128B row
            int nfull = cnt & ~15;
            int it = 0;
            for (; it < nfull; it += 16) {       // mask-free full steps, 4 loads in flight
                int o0 = __shfl(rof, it + grp, 64) + qoff;
                int o1 = __shfl(rof, it + 4 + grp, 64) + qoff;
                int o2 = __shfl(rof, it + 8 + grp, 64) + qoff;
                int o3 = __shfl(rof, it + 12 + grp, 64) + qoff;
                uint2 u0 = *(const uint2*)(h1c + (uint32_t)o0);
                uint2 u1 = *(const uint2*)(h1c + (uint32_t)o1);
                uint2 u2 = *(const uint2*)(h1c + (uint32_t)o2);
                uint2 u3 = *(const uint2*)(h1c + (uint32_t)o3);
                a0 += __builtin_amdgcn_cvt_pk_f32_fp8(u0.x, false);
                a1 += __builtin_amdgcn_cvt_pk_f32_fp8(u0.x, true);
                a2 += __builtin_amdgcn_cvt_pk_f32_fp8(u0.y, false);
                a3 += __builtin_amdgcn_cvt_pk_f32_fp8(u0.y, true);
                a0 += __builtin_amdgcn_cvt_pk_f32_fp8(u1.x, false);
                a1 += __builtin_amdgcn_cvt_pk_f32_fp8(u1.x, true);
                a2 += __builtin_amdgcn_cvt_pk_f32_fp8(u1.y, false);
                a3 += __builtin_amdgcn_cvt_pk_f32_fp8(u1.y, true);
                a0 += __builtin_amdgcn_cvt_pk_f32_fp8(u2.x, false);
                a1 += __builtin_amdgcn_cvt_pk_f32_fp8(u2.x, true);
                a2 += __builtin_amdgcn_cvt_pk_f32_fp8(u2.y, false);
                a3 += __builtin_amdgcn_cvt_pk_f32_fp8(u2.y, true);
                a0 += __builtin_amdgcn_cvt_pk_f32_fp8(u3.x, false);
                a1 += __builtin_amdgcn_cvt_pk_f32_fp8(u3.x, true);
                a2 += __builtin_amdgcn_cvt_pk_f32_fp8(u3.y, false);
                a3 += __builtin_amdgcn_cvt_pk_f32_fp8(u3.y, true);
            }
            if (it < cnt) {                      // one masked tail step (<=15 edges)
                int e0 = it + grp;               // e0+12 <= 63 always
                int o0 = __shfl(rof, e0, 64) + qoff;
                int o1 = __shfl(rof, e0 + 4, 64) + qoff;
                int o2 = __shfl(rof, e0 + 8, 64) + qoff;
                int o3 = __shfl(rof, e0 + 12, 64) + qoff;
                float mv0 = (e0 < cnt) ? 1.f : 0.f;
                float mv1 = (e0 + 4 < cnt) ? 1.f : 0.f;
                float mv2 = (e0 + 8 < cnt) ? 1.f : 0.f;
                float mv3 = (e0 + 12 < cnt) ? 1.f : 0.f;
                f32x2 m0 = {mv0, mv0}, m1 = {mv1, mv1}, m2 = {mv2, mv2}, m3 = {mv3, mv3};
                uint2 u0 = *(const uint2*)(h1c + (uint32_t)o0);
                uint2 u1 = *(const uint2*)(h1c + (uint32_t)o1);
                uint2 u2 = *(const uint2*)(h1c + (uint32_t)o2);
                uint2 u3 = *(const uint2*)(h1c + (uint32_t)o3);
                a0 += __builtin_amdgcn_cvt_pk_f32_fp8(u0.x, false) * m0;
                a1 += __builtin_amdgcn_cvt_pk_f32_fp8(u0.x, true) * m0;
                a2 += __builtin_amdgcn_cvt_pk_f32_fp8(u0.y, false) * m0;
                a3 += __builtin_amdgcn_cvt_pk_f32_fp8(u0.y, true) * m0;
                a0 += __builtin_amdgcn_cvt_pk_f32_fp8(u1.x, false) * m1;
                a1 += __builtin_amdgcn_cvt_pk_f32_fp8(u1.x, true) * m1;
                a2 += __builtin_amdgcn_cvt_pk_f32_fp8(u1.y, false) * m1;
                a3 += __builtin_amdgcn_cvt_pk_f32_fp8(u1.y, true) * m1;
                a0 += __builtin_amdgcn_cvt_pk_f32_fp8(u2.x, false) * m2;
                a1 += __builtin_amdgcn_cvt_pk_f32_fp8(u2.x, true) * m2;
                a2 += __builtin_amdgcn_cvt_pk_f32_fp8(u2.y, false) * m2;
                a3 += __builtin_amdgcn_cvt_pk_f32_fp8(u2.y, true) * m2;
                a0 += __builtin_amdgcn_cvt_pk_f32_fp8(u3.x, false) * m3;
                a1 += __builtin_amdgcn_cvt_pk_f32_fp8(u3.x, true) * m3;
                a2 += __builtin_amdgcn_cvt_pk_f32_fp8(u3.y, false) * m3;
                a3 += __builtin_amdgcn_cvt_pk_f32_fp8(u3.y, true) * m3;
            }
            i += cnt;
        }
        float ac[8] = {a0.x, a0.y, a1.x, a1.y, a2.x, a2.y, a3.x, a3.y};
        // fold the 4 edge-groups (lane bits 4,5)
#pragma unroll
        for (int j = 0; j < 8; ++j) {
            ac[j] += __shfl_xor(ac[j], 16, 64);
            ac[j] += __shfl_xor(ac[j], 32, 64);
        }
        if (lane < 16) {
            float sc = rs_in[w];
            float f0, f1;
            uint32_t o0, o1, o2, o3;
            f0 = fmaxf(fmaf(ac[0], sc, blo.x), 0.f); f1 = fmaxf(fmaf(ac[1], sc, blo.y), 0.f);
            o0 = (uint32_t)(unsigned short)f2bf(f0) | ((uint32_t)(unsigned short)f2bf(f1) << 16);
            f0 = fmaxf(fmaf(ac[2], sc, blo.z), 0.f); f1 = fmaxf(fmaf(ac[3], sc, blo.w), 0.f);
            o1 = (uint32_t)(unsigned short)f2bf(f0) | ((uint32_t)(unsigned short)f2bf(f1) << 16);
            f0 = fmaxf(fmaf(ac[4], sc, bhi.x), 0.f); f1 = fmaxf(fmaf(ac[5], sc, bhi.y), 0.f);
            o2 = (uint32_t)(unsigned short)f2bf(f0) | ((uint32_t)(unsigned short)f2bf(f1) << 16);
            f0 = fmaxf(fmaf(ac[6], sc, bhi.z), 0.f); f1 = fmaxf(fmaf(ac[7], sc, bhi.w), 0.f);
            o3 = (uint32_t)(unsigned short)f2bf(f0) | ((uint32_t)(unsigned short)f2bf(f1) << 16);
            int woff = (wv * 256 + ql * 16) ^ ((wv & 7) << 4);
            *(uint4*)((char*)x1s + woff) = make_uint4(o0, o1, o2, o3);
        }
    }
    __syncthreads();
    int vr = min(4, N - w_base);
    if (wv < 3) {
        // W2 fragments loaded here (after edge phase) to keep hot-loop VGPR pressure low
        short8 wf0 = *(const short8*)&Wg2[((wv * 4 + 0) * 64 + lane) * 8];
        short8 wf1 = *(const short8*)&Wg2[((wv * 4 + 1) * 64 + lane) * 8];
        short8 wf2 = *(const short8*)&Wg2[((wv * 4 + 2) * 64 + lane) * 8];
        short8 wf3 = *(const short8*)&Wg2[((wv * 4 + 3) * 64 + lane) * 8];
        int row = lane & 15, kc = lane >> 4;
        int rbase = row * 256 + kc * 16;
        int swz = (row & 7) << 4;
        f32x4 c = {};
        c = __builtin_amdgcn_mfma_f32_16x16x32_bf16(*(short8*)((char*)x1s + ((rbase + 0) ^ swz)),   wf0, c, 0, 0, 0);
        c = __builtin_amdgcn_mfma_f32_16x16x32_bf16(*(short8*)((char*)x1s + ((rbase + 64) ^ swz)),  wf1, c, 0, 0, 0);
        c = __builtin_amdgcn_mfma_f32_16x16x32_bf16(*(short8*)((char*)x1s + ((rbase + 128) ^ swz)), wf2, c, 0, 0, 0);
        c = __builtin_amdgcn_mfma_f32_16x16x32_bf16(*(short8*)((char*)x1s + ((rbase + 192) ^ swz)), wf3, c, 0, 0, 0);
        int cc = wv * 16 + row;     // output column 0..47 (only <40 valid)
        if (cc < OUT_DIM && kc == 0) {   // C rows 0..3 live in kc==0 lanes
            float s0 = rs_out[w_base + 0];
            float s1 = (vr > 1) ? rs_out[w_base + 1] : 0.f;
            float s2 = (vr > 2) ? rs_out[w_base + 2] : 0.f;
            float s3 = (vr > 3) ? rs_out[w_base + 3] : 0.f;
            int pk = __builtin_amdgcn_cvt_pk_fp8_f32(c[0] * s0, c[1] * s1, 0, false);
            pk = __builtin_amdgcn_cvt_pk_fp8_f32(c[2] * s2, c[3] * s3, pk, true);
            hs2[cc] = (uint32_t)pk;      // banks 0..15 per wave: conflict-free
        }
    }
    __syncthreads();
    if (t < 64) {                        // assemble padded 64B rows: dword d of row `node`
        int node = t >> 4, d = t & 15;
        uint32_t v = 0;
        if (d < 10) {
            int sh = node * 8;
            uint32_t b0 = (hs2[4 * d + 0] >> sh) & 0xffu;
            uint32_t b1 = (hs2[4 * d + 1] >> sh) & 0xffu;
            uint32_t b2 = (hs2[4 * d + 2] >> sh) & 0xffu;
            uint32_t b3 = (hs2[4 * d + 3] >> sh) & 0xffu;
            v = b0 | (b1 << 8) | (b2 << 16) | (b3 << 24);
        }
        if (node < vr) h2f[(size_t)(w_base + node) * 16 + d] = v;
    }
}

// ---------------- SpMM2 (fp8, 64B-padded rows) + bias + log_softmax ----------------
// 8 lanes/edge x uint2; 32 edges per it-step = 4 independent loads in flight; mask-free hot loop.
__global__ __launch_bounds__(256) void k_spmm2(const char* __restrict__ h2c, const int* __restrict__ rp,
                                               const int* __restrict__ col, const float* __restrict__ rs_in,
                                               const float* __restrict__ b2, float* __restrict__ out, int n) {
    int w = (blockIdx.x * 256 + threadIdx.x) >> 6;
    int lane = threadIdx.x & 63;
    if (w >= n) return;
    int grp = lane >> 3, fl = lane & 7;       // fl: feature-byte group (fl<5 real, 5..7 pad=0)
    int qoff = fl << 3;
    int s = rp[w], e = rp[w + 1];
    f32x2 a0 = {0.f, 0.f}, a1 = {0.f, 0.f}, a2 = {0.f, 0.f}, a3 = {0.f, 0.f};
    int i = s;
    while (i < e) {
        int cnt = min(64, e - i);
        int cl = (lane < cnt) ? lane : cnt - 1;
        int rof = col[i + cl] << 6;           // byte offset of 64B row
        int nfull = cnt & ~31;
        int it = 0;
        for (; it < nfull; it += 32) {        // mask-free full steps
            int o0 = __shfl(rof, it + grp, 64) + qoff;
            int o1 = __shfl(rof, it + 8 + grp, 64) + qoff;
            int o2 = __shfl(rof, it + 16 + grp, 64) + qoff;
            int o3 = __shfl(rof, it + 24 + grp, 64) + qoff;
            uint2 u0 = *(const uint2*)(h2c + (uint32_t)o0);
            uint2 u1 = *(const uint2*)(h2c + (uint32_t)o1);
            uint2 u2 = *(const uint2*)(h2c + (uint32_t)o2);
            uint2 u3 = *(const uint2*)(h2c + (uint32_t)o3);
            a0 += __builtin_amdgcn_cvt_pk_f32_fp8(u0.x, false);
            a1 += __builtin_amdgcn_cvt_pk_f32_fp8(u0.x, true);
            a2 += __builtin_amdgcn_cvt_pk_f32_fp8(u0.y, false);
            a3 += __builtin_amdgcn_cvt_pk_f32_fp8(u0.y, true);
            a0 += __builtin_amdgcn_cvt_pk_f32_fp8(u1.x, false);
            a1 += __builtin_amdgcn_cvt_pk_f32_fp8(u1.x, true);
            a2 += __builtin_amdgcn_cvt_pk_f32_fp8(u1.y, false);
            a3 += __builtin_amdgcn_cvt_pk_f32_fp8(u1.y, true);
            a0 += __builtin_amdgcn_cvt_pk_f32_fp8(u2.x, false);
            a1 += __builtin_amdgcn_cvt_pk_f32_fp8(u2.x, true);
            a2 += __builtin_amdgcn_cvt_pk_f32_fp8(u2.y, false);
            a3 += __builtin_amdgcn_cvt_pk_f32_fp8(u2.y, true);
            a0 += __builtin_amdgcn_cvt_pk_f32_fp8(u3.x, false);
            a1 += __builtin_amdgcn_cvt_pk_f32_fp8(u3.x, true);
            a2 += __builtin_amdgcn_cvt_pk_f32_fp8(u3.y, false);
            a3 += __builtin_amdgcn_cvt_pk_f32_fp8(u3.y, true);
        }
        if (it < cnt) {                       // one masked tail step (<=31 edges)
            int e0 = it + grp;                // e0+24 <= 63 always
            int o0 = __shfl(rof, e0, 64) + qoff;
            int o1 = __shfl(rof, e0 + 8, 64) + qoff;
            int o2 = __shfl(rof, e0 + 16, 64) + qoff;
            int o3 = __shfl(rof, e0 + 24, 64) + qoff;
            float mv0 = (e0 < cnt) ? 1.f : 0.f;
            float mv1 = (e0 + 8 < cnt) ? 1.f : 0.f;
            float mv2 = (e0 + 16 < cnt) ? 1.f : 0.f;
            float mv3 = (e0 + 24 < cnt) ? 1.f : 0.f;
            f32x2 m0 = {mv0, mv0}, m1 = {mv1, mv1}, m2 = {mv2, mv2}, m3 = {mv3, mv3};
            uint2 u0 = *(const uint2*)(h2c + (uint32_t)o0);
            uint2 u1 = *(const uint2*)(h2c + (uint32_t)o1);
            uint2 u2 = *(const uint2*)(h2c + (uint32_t)o2);
            uint2 u3 = *(const uint2*)(h2c + (uint32_t)o3);
            a0 += __builtin_amdgcn_cvt_pk_f32_fp8(u0.x, false) * m0;
            a1 += __builtin_amdgcn_cvt_pk_f32_fp8(u0.x, true) * m0;
            a2 += __builtin_amdgcn_cvt_pk_f32_fp8(u0.y, false) * m0;
            a3 += __builtin_amdgcn_cvt_pk_f32_fp8(u0.y, true) * m0;
            a0 += __builtin_amdgcn_cvt_pk_f32_fp8(u1.x, false) * m1;
            a1 += __builtin_amdgcn_cvt_pk_f32_fp8(u1.x, true) * m1;
            a2 += __builtin_amdgcn_cvt_pk_f32_fp8(u1.y, false) * m1;
            a3 += __builtin_amdgcn_cvt_pk_f32_fp8(u1.y, true) * m1;
            a0 += __builtin_amdgcn_cvt_pk_f32_fp8(u2.x, false) * m2;
            a1 += __builtin_amdgcn_cvt_pk_f32_fp8(u2.x, true) * m2;
            a2 += __builtin_amdgcn_cvt_pk_f32_fp8(u2.y, false) * m2;
            a3 += __builtin_amdgcn_cvt_pk_f32_fp8(u2.y, true) * m2;
            a0 += __builtin_amdgcn_cvt_pk_f32_fp8(u3.x, false) * m3;
            a1 += __builtin_amdgcn_cvt_pk_f32_fp8(u3.x, true) * m3;
            a2 += __builtin_amdgcn_cvt_pk_f32_fp8(u3.y, false) * m3;
            a3 += __builtin_amdgcn_cvt_pk_f32_fp8(u3.y, true) * m3;
        }
        i += cnt;
    }
    float ac[8] = {a0.x, a0.y, a1.x, a1.y, a2.x, a2.y, a3.x, a3.y};
    // fold 8 edge-groups (lane bits 3,4,5)
#pragma unroll
    for (int j = 0; j < 8; ++j) {
        ac[j] += __shfl_xor(ac[j], 8, 64);
        ac[j] += __shfl_xor(ac[j], 16, 64);
        ac[j] += __shfl_xor(ac[j], 32, 64);
    }
    bool act = lane < 5;
    float sc = rs_in[w];
    int bb = (fl < 5) ? fl * 8 : 0;           // guard b2 OOB for pad lanes
    float val[8];
#pragma unroll
    for (int j = 0; j < 8; ++j)
        val[j] = fmaf(ac[j], sc, b2[bb + j]);
    float pm = -INFINITY;
    if (act) {
        pm = val[0];
#pragma unroll
        for (int j = 1; j < 8; ++j) pm = fmaxf(pm, val[j]);
    }
    pm = fmaxf(pm, __shfl_xor(pm, 4, 8));
    pm = fmaxf(pm, __shfl_xor(pm, 2, 8));
    pm = fmaxf(pm, __shfl_xor(pm, 1, 8));
    float ex = 0.f;
    if (act) {
#pragma unroll
        for (int j = 0; j < 8; ++j) ex += expf(val[j] - pm);
    }
    ex += __shfl_xor(ex, 4, 8);
    ex += __shfl_xor(ex, 2, 8);
    ex += __shfl_xor(ex, 1, 8);
    if (act) {
        float l = pm + logf(ex);
        float4 o0 = {val[0] - l, val[1] - l, val[2] - l, val[3] - l};
        float4 o1 = {val[4] - l, val[5] - l, val[6] - l, val[7] - l};
        float* op = out + (size_t)w * OUT_DIM + lane * 8;
        *(float4*)op = o0;
        *(float4*)(op + 4) = o1;
    }
}

// ---------------- launch ----------------

extern "C" void kernel_launch(void* const* d_in, const int* in_sizes, int n_in,
                              void* d_out, int out_size, void* d_ws, size_t ws_size,
                              hipStream_t stream) {
    const int N = in_sizes[0] / IN_DIM;
    const int E = in_sizes[5];
    const float* h  = (const float*)d_in[0];
    const float* W1 = (const float*)d_in[1];
    const float* b1 = (const float*)d_in[2];
    const float* W2 = (const float*)d_in[3];
    const float* b2 = (const float*)d_in[4];
    const int* src  = (const int*)d_in[5];
    const int* dst  = (const int*)d_in[6];
    float* out = (float*)d_out;

    const int NBINS  = (N + BIN_SIZE - 1) >> BIN_SHIFT;   // 98
    const int NCHUNK = (E + CHUNK - 1) / CHUNK;           // 782

    char* w = (char*)d_ws;
    size_t off = 0;
    auto alloc = [&](size_t bytes) -> void* {
        void* p = w + off;
        off += (bytes + 255) & ~(size_t)255;
        return p;
    };
    int* deg_in   = (int*)alloc((size_t)N * 4);
    int* deg_out  = (int*)alloc((size_t)N * 4);
    int* row_ptr  = (int*)alloc((size_t)(N + 1) * 4);
    int* bsum     = (int*)alloc(1024 * 4);
    float* rs_out = (float*)alloc((size_t)N * 4);
    float* rs_in  = (float*)alloc((size_t)N * 4);
    int* col      = (int*)alloc((size_t)E * 4);
    int* bboD     = (int*)alloc((size_t)NCHUNK * (NBINS + 1) * 4);
    int* bboS     = (int*)alloc((size_t)NCHUNK * (NBINS + 1) * 4);
    short* Wg     = (short*)alloc((size_t)8 * 8 * 64 * 8 * 2);    // 64 KB
    short* Wg2    = (short*)alloc((size_t)3 * 4 * 64 * 8 * 2);    // 12 KB
    float* b1p    = (float*)alloc((size_t)HID * 4);
    uint32_t* stD = (uint32_t*)alloc((size_t)E * 4);              // 12.8 MB
    unsigned short* stS = (unsigned short*)alloc((size_t)E * 2);  // 6.4 MB
    uint32_t* h1f = (uint32_t*)alloc((size_t)N * HID);            // fp8 [N][128], 12.8 MB (own buffer: col+gemm1 overlap)
    uint32_t* h2f = (uint32_t*)alloc((size_t)N * 64);             // fp8 [N][64] (40 real + 24 pad), 6.4 MB

    int gN = (N + 255) / 256;
    int NB = (N + 1023) / 1024;
    int Z = (N + 3) / 4;
    int setup_units = 8192 + 3 * 4 * 64 * 8 + HID + 2 * Z;
    int setupBlocks = (setup_units + 255) / 256;

    k_init<<<setupBlocks + NCHUNK, 256, 0, stream>>>(W1, W2, b1, Wg, Wg2, b1p, deg_in, deg_out, Z,
                                                     src, dst, stD, stS, bboD, bboS, E, NBINS, setupBlocks);
    k_deg<<<dim3(NBINS, GSPLIT, 2), 256, 0, stream>>>(stD, bboD, stS, bboS, deg_in, deg_out, NCHUNK, NBINS);
    k_scan1<<<NB, 256, 0, stream>>>(deg_in, row_ptr, bsum, rs_in, N);
    k_scan3<<<gN, 256, 0, stream>>>(row_ptr, bsum, deg_out, rs_out, N, E, NB);
    k_colgemm1<<<NBINS + (N + 63) / 64, 256, 0, stream>>>(stD, bboD, row_ptr, col, NCHUNK, NBINS,
                                                          h, Wg, rs_out, h1f, N);
    k_spmm1f<<<(N + 3) / 4, 256, 0, stream>>>((const char*)h1f, row_ptr, col, rs_in, rs_out, b1p, Wg2, h2f, N);
    k_spmm2<<<(N + 3) / 4, 256, 0, stream>>>((const char*)h2f, row_ptr, col, rs_in, b2, out, N);
}

// Round 10
// 407.500 us; speedup vs baseline: 1.1287x; 1.1287x over previous
//
#include <hip/hip_runtime.h>
#include <hip/hip_bf16.h>
#include <cstddef>
#include <cstdint>

#define IN_DIM 256
#define HID 128
#define OUT_DIM 40

#define CHUNK 4096      // edges per binscatter block (LDS-staged counting sort)
#define BIN_SHIFT 10    // 1024 nodes per bin
#define BIN_SIZE 1024
#define MAXB 128        // >= NBINS+1
#define GSPLIT 8        // blocks per bin for deg/col kernels

typedef __attribute__((ext_vector_type(8))) short short8;
typedef __attribute__((ext_vector_type(4))) float f32x4;
typedef __attribute__((ext_vector_type(2))) float f32x2;

__device__ inline short f2bf(float f) {
    __hip_bfloat16 b = __float2bfloat16(f);   // RNE
    return __builtin_bit_cast(short, b);
}
__device__ inline float bf2f(unsigned short u) {
    unsigned int v = (unsigned int)u << 16;
    return __builtin_bit_cast(float, v);
}
// feature permutation for h1/x1 storage: slot p holds feature (p>>3) + 16*(p&7).
__device__ inline int permf(int p) { return (p >> 3) + 16 * (p & 7); }

// ---------------- merged init: [0,setupBlocks) = W repacks + deg zeroing; rest = binscatter ----------------
// Binscatter: LDS-staged chunk-private counting sort (avoids ~9x partial-line write amplification
// of scattered 4B/2B global stores — measured R5: WRITE_SIZE 113 MB for 12.5 MB payload).
__global__ __launch_bounds__(256) void k_init(const float* __restrict__ W1, const float* __restrict__ W2,
                                              const float* __restrict__ b1, short* __restrict__ Wg,
                                              short* __restrict__ Wg2, float* __restrict__ b1p,
                                              int* __restrict__ deg_in, int* __restrict__ deg_out, int Z,
                                              const int* __restrict__ src, const int* __restrict__ dst,
                                              uint32_t* __restrict__ stD, unsigned short* __restrict__ stS,
                                              int* __restrict__ bboD, int* __restrict__ bboS,
                                              int E, int NBINS, int setupBlocks) {
    __shared__ __align__(16) uint32_t sgD[CHUNK];         // 16 KB
    __shared__ __align__(16) unsigned short sgS[CHUNK];   // 8 KB
    __shared__ int hD[MAXB], hS[MAXB], sd[MAXB];
    int t = threadIdx.x;
    if (blockIdx.x < setupBlocks) {
        int flat = blockIdx.x * 256 + t;
        if (flat < 8192) {                        // W1: fp32 [256][128] -> bf16 fragments [nt][ks][lane][8]
            int k = flat >> 5;
            int n0 = (flat & 31) * 4;
            float4 v = *(const float4*)(W1 + (size_t)k * HID + n0);
            int ks = k >> 5, quad = (k >> 3) & 3, j = k & 7;
            float vv[4] = {v.x, v.y, v.z, v.w};
#pragma unroll
            for (int e = 0; e < 4; ++e) {
                int n = n0 + e;
                int nt = n >> 4;
                int ln = (n & 15) | (quad << 4);
                Wg[(((nt * 8 + ks) * 64) + ln) * 8 + j] = f2bf(vv[e]);
            }
            return;
        }
        flat -= 8192;
        if (flat < 3 * 4 * 64 * 8) {              // W2: fp32 [128][40] -> bf16 B-fragments (pad cols 40->48)
            int f = flat >> 9;
            int ln = (flat >> 3) & 63;
            int j = flat & 7;
            int nt = f >> 2, ks = f & 3;
            int q = ks * 32 + (ln >> 4) * 8 + j;  // x1 slot (permuted feature index)
            int c = nt * 16 + (ln & 15);          // output col
            float v = (c < OUT_DIM) ? W2[(size_t)permf(q) * OUT_DIM + c] : 0.f;
            Wg2[flat] = f2bf(v);
            return;
        }
        flat -= 3 * 4 * 64 * 8;
        if (flat < HID) { b1p[flat] = b1[permf(flat)]; return; }
        flat -= HID;
        if (flat < Z) { *(int4*)(deg_in + flat * 4) = make_int4(0, 0, 0, 0); return; }
        flat -= Z;
        if (flat < Z) { *(int4*)(deg_out + flat * 4) = make_int4(0, 0, 0, 0); }
        return;
    }
    // ---- binscatter ----
    int j = blockIdx.x - setupBlocks;
    int base = j * CHUNK;
    int nE = min(CHUNK, E - base);
    int NB1 = NBINS + 1;
    for (int i = t; i < MAXB; i += 256) { hD[i] = 0; hS[i] = 0; }
    __syncthreads();
    for (int i = t; i < nE; i += 256) {
        atomicAdd(&hD[dst[base + i] >> BIN_SHIFT], 1);
        atomicAdd(&hS[src[base + i] >> BIN_SHIFT], 1);
    }
    __syncthreads();
    // scan D
    if (t < MAXB) sd[t] = hD[t];
    __syncthreads();
    for (int off = 1; off < MAXB; off <<= 1) {
        int x = 0;
        if (t < MAXB && t >= off) x = sd[t - off];
        __syncthreads();
        if (t < MAXB) sd[t] += x;
        __syncthreads();
    }
    if (t < MAXB) {
        int h = hD[t];
        int c = sd[t] - h;
        hD[t] = c;                                  // hD becomes cursor
        if (t < NBINS) bboD[(size_t)j * NB1 + t] = c;
    }
    if (t == NBINS) bboD[(size_t)j * NB1 + NBINS] = nE;
    __syncthreads();
    // scan S
    if (t < MAXB) sd[t] = hS[t];
    __syncthreads();
    for (int off = 1; off < MAXB; off <<= 1) {
        int x = 0;
        if (t < MAXB && t >= off) x = sd[t - off];
        __syncthreads();
        if (t < MAXB) sd[t] += x;
        __syncthreads();
    }
    if (t < MAXB) {
        int h = hS[t];
        int c = sd[t] - h;
        hS[t] = c;                                  // hS becomes cursor
        if (t < NBINS) bboS[(size_t)j * NB1 + t] = c;
    }
    if (t == NBINS) bboS[(size_t)j * NB1 + NBINS] = nE;
    __syncthreads();
    // scatter into LDS staging
    for (int i = t; i < nE; i += 256) {
        int s = src[base + i], d = dst[base + i];
        int pD = atomicAdd(&hD[d >> BIN_SHIFT], 1);
        sgD[pD] = ((uint32_t)(d & (BIN_SIZE - 1)) << 17) | (uint32_t)s;
        int pS = atomicAdd(&hS[s >> BIN_SHIFT], 1);
        sgS[pS] = (unsigned short)(s & (BIN_SIZE - 1));
    }
    __syncthreads();
    // coalesced flush
    int nh = nE >> 1;
    uint2* dD = (uint2*)(stD + base);
    const uint2* sD = (const uint2*)sgD;
    for (int i = t; i < nh; i += 256) dD[i] = sD[i];
    uint32_t* dS = (uint32_t*)(stS + base);
    const uint32_t* sS = (const uint32_t*)sgS;
    for (int i = t; i < nh; i += 256) dS[i] = sS[i];
    if ((nE & 1) && t == 0) { stD[base + nE - 1] = sgD[nE - 1]; stS[base + nE - 1] = sgS[nE - 1]; }
}

// ---------------- merged degree kernel: z==0 dst (+hsave persist), z==1 src ----------------
// 4 chunk-segments in flight per wave iteration (latency chains overlap).
__global__ __launch_bounds__(256) void k_deg(const uint32_t* __restrict__ stD, const int* __restrict__ bboD,
                                             const unsigned short* __restrict__ stS, const int* __restrict__ bboS,
                                             int* __restrict__ deg_in, int* __restrict__ deg_out,
                                             int* __restrict__ hsave, int nchunk, int NBINS) {
    __shared__ int hist[BIN_SIZE];
    int b = blockIdx.x, g = blockIdx.y, t = threadIdx.x;
    int wv = t >> 6, lane = t & 63;
    int NB1 = NBINS + 1;
    for (int i = t; i < BIN_SIZE; i += 256) hist[i] = 0;
    __syncthreads();
    int base = b << BIN_SHIFT;
    if (blockIdx.z == 0) {
        for (int jj = g * 4 + wv; jj < nchunk; jj += 128) {
            int s[4], e[4];
            uint32_t v[4];
            bool av[4];
#pragma unroll
            for (int q = 0; q < 4; ++q) {
                int j = jj + q * 32;
                bool jv = j < nchunk;
                s[q] = jv ? bboD[(size_t)j * NB1 + b] : 0;
                e[q] = jv ? bboD[(size_t)j * NB1 + b + 1] : 0;
            }
#pragma unroll
            for (int q = 0; q < 4; ++q) {
                av[q] = s[q] + lane < e[q];
                v[q] = av[q] ? stD[(size_t)(jj + q * 32) * CHUNK + s[q] + lane] : 0u;
            }
#pragma unroll
            for (int q = 0; q < 4; ++q)
                if (av[q]) atomicAdd(&hist[v[q] >> 17], 1);
#pragma unroll
            for (int q = 0; q < 4; ++q) {
                int j = jj + q * 32;
                for (int i = s[q] + lane + 64; i < e[q]; i += 64)
                    atomicAdd(&hist[stD[(size_t)j * CHUNK + i] >> 17], 1);
            }
        }
        __syncthreads();
        int* hp = hsave + ((size_t)(b * GSPLIT + g) << BIN_SHIFT);
        for (int i = t; i < BIN_SIZE; i += 256) {
            int v = hist[i];
            hp[i] = v;
            if (v) atomicAdd(&deg_in[base + i], v);
        }
    } else {
        for (int jj = g * 4 + wv; jj < nchunk; jj += 128) {
            int s[4], e[4];
            unsigned short v[4];
            bool av[4];
#pragma unroll
            for (int q = 0; q < 4; ++q) {
                int j = jj + q * 32;
                bool jv = j < nchunk;
                s[q] = jv ? bboS[(size_t)j * NB1 + b] : 0;
                e[q] = jv ? bboS[(size_t)j * NB1 + b + 1] : 0;
            }
#pragma unroll
            for (int q = 0; q < 4; ++q) {
                av[q] = s[q] + lane < e[q];
                v[q] = av[q] ? stS[(size_t)(jj + q * 32) * CHUNK + s[q] + lane] : (unsigned short)0;
            }
#pragma unroll
            for (int q = 0; q < 4; ++q)
                if (av[q]) atomicAdd(&hist[v[q]], 1);
#pragma unroll
            for (int q = 0; q < 4; ++q) {
                int j = jj + q * 32;
                for (int i = s[q] + lane + 64; i < e[q]; i += 64)
                    atomicAdd(&hist[stS[(size_t)j * CHUNK + i]], 1);
            }
        }
        __syncthreads();
        for (int i = t; i < BIN_SIZE; i += 256) {
            int v = hist[i];
            if (v) atomicAdd(&deg_out[base + i], v);
        }
    }
}

__global__ __launch_bounds__(256) void k_scan1(const int* __restrict__ deg, int* __restrict__ out,
                                               int* __restrict__ bsum, float* __restrict__ rs_in, int n) {
    __shared__ int sd[256];
    int t = threadIdx.x, b = blockIdx.x;
    int base = b * 1024 + t * 4;
    int v0 = 0, v1 = 0, v2 = 0, v3 = 0;
    if (base + 0 < n) v0 = deg[base + 0];
    if (base + 1 < n) v1 = deg[base + 1];
    if (base + 2 < n) v2 = deg[base + 2];
    if (base + 3 < n) v3 = deg[base + 3];
    if (base + 0 < n) rs_in[base + 0] = rsqrtf((float)max(v0, 1));
    if (base + 1 < n) rs_in[base + 1] = rsqrtf((float)max(v1, 1));
    if (base + 2 < n) rs_in[base + 2] = rsqrtf((float)max(v2, 1));
    if (base + 3 < n) rs_in[base + 3] = rsqrtf((float)max(v3, 1));
    int ts = v0 + v1 + v2 + v3;
    sd[t] = ts;
    __syncthreads();
    for (int off = 1; off < 256; off <<= 1) {
        int x = 0;
        if (t >= off) x = sd[t - off];
        __syncthreads();
        sd[t] += x;
        __syncthreads();
    }
    int excl = sd[t] - ts;
    if (base + 0 < n) out[base + 0] = excl;
    if (base + 1 < n) out[base + 1] = excl + v0;
    if (base + 2 < n) out[base + 2] = excl + v0 + v1;
    if (base + 3 < n) out[base + 3] = excl + v0 + v1 + v2;
    if (t == 255) bsum[b] = sd[255];
}

// scan3 with the (tiny) bsum scan done redundantly per block (removes the 1-block scan2 launch).
// Requires NB <= 128 (N <= 131072; here N = 100000 -> NB = 98).
__global__ __launch_bounds__(256) void k_scan3(int* __restrict__ row_ptr, const int* __restrict__ bsum,
                                               int* __restrict__ cursor, const int* __restrict__ deg_out,
                                               float* __restrict__ rs_out, int n, int E, int NB) {
    __shared__ int sb[128];
    int t = threadIdx.x;
    if (t < 128) sb[t] = (t < NB) ? bsum[t] : 0;
    __syncthreads();
    for (int off = 1; off < 128; off <<= 1) {
        int x = 0;
        if (t < 128 && t >= off) x = sb[t - off];
        __syncthreads();
        if (t < 128) sb[t] += x;
        __syncthreads();
    }
    int i = blockIdx.x * 256 + threadIdx.x;
    if (i < n) {
        int blk = i >> 10;
        int add = (blk > 0) ? sb[blk - 1] : 0;     // exclusive prefix of block sums
        int v = row_ptr[i] + add;
        row_ptr[i] = v;
        cursor[i] = v;
        rs_out[i] = rsqrtf((float)max(deg_out[i], 1));
    }
    if (i == 0) row_ptr[n] = E;
}

// ---------------- merged col + GEMM1 (one launch; complementary pipes overlap) ----------------
// [0, colBlocks): col scatter (reuses k_deg's saved histograms; ONE pass over stD),
//                 4 chunk-segments in flight per wave iteration.
// [colBlocks, ...): GEMM1 — LDS-free (R8): lane's MFMA A-fragment = 8 consecutive k of one row,
// loaded straight from global as 2x float4.
__global__ __launch_bounds__(256) void k_colgemm1(const uint32_t* __restrict__ stD, const int* __restrict__ bboD,
                                                  const int* __restrict__ hsave, int* __restrict__ cursor,
                                                  int* __restrict__ col, int nchunk, int NBINS, int colBlocks,
                                                  const float* __restrict__ A, const short* __restrict__ Wg,
                                                  const float* __restrict__ rs_out, uint32_t* __restrict__ h1f,
                                                  int M) {
    __shared__ int hist[BIN_SIZE];            // col histogram (4 KB) — only LDS in this kernel
    int t = threadIdx.x;
    if (blockIdx.x < colBlocks) {
        int b = blockIdx.x / GSPLIT, g = blockIdx.x % GSPLIT;
        int wv = t >> 6, lane = t & 63;
        int NB1 = NBINS + 1;
        int base = b << BIN_SHIFT;
        const int* hp = hsave + ((size_t)(b * GSPLIT + g) << BIN_SHIFT);
        for (int i = t; i < BIN_SIZE; i += 256) {
            int v = hp[i];
            hist[i] = v ? atomicAdd(&cursor[base + i], v) : 0;
        }
        __syncthreads();
        for (int jj = g * 4 + wv; jj < nchunk; jj += 128) {
            int s[4], e[4];
            uint32_t v[4];
            bool av[4];
#pragma unroll
            for (int q = 0; q < 4; ++q) {
                int j = jj + q * 32;
                bool jv = j < nchunk;
                s[q] = jv ? bboD[(size_t)j * NB1 + b] : 0;
                e[q] = jv ? bboD[(size_t)j * NB1 + b + 1] : 0;
            }
#pragma unroll
            for (int q = 0; q < 4; ++q) {
                av[q] = s[q] + lane < e[q];
                v[q] = av[q] ? stD[(size_t)(jj + q * 32) * CHUNK + s[q] + lane] : 0u;
            }
#pragma unroll
            for (int q = 0; q < 4; ++q) {
                if (av[q]) {
                    int pos = atomicAdd(&hist[v[q] >> 17], 1);
                    col[pos] = (int)(v[q] & 0x1FFFFu);
                }
            }
#pragma unroll
            for (int q = 0; q < 4; ++q) {
                int j = jj + q * 32;
                for (int i = s[q] + lane + 64; i < e[q]; i += 64) {
                    uint32_t vv = stD[(size_t)j * CHUNK + i];
                    int pos = atomicAdd(&hist[vv >> 17], 1);
                    col[pos] = (int)(vv & 0x1FFFFu);
                }
            }
        }
        return;
    }
    // ---- GEMM1 (LDS-free) ----
    int lane = t & 63, wv = t >> 6;
    int block_row = (blockIdx.x - colBlocks) * 64;
    int row = block_row + wv * 16 + (lane & 15);
    bool valid = row < M;
    const float* ap = A + (size_t)row * IN_DIM + (lane >> 4) * 8;
    f32x4 acc[8] = {};
#pragma unroll
    for (int ks = 0; ks < 8; ++ks) {
        float4 va = {0.f, 0.f, 0.f, 0.f}, vb = {0.f, 0.f, 0.f, 0.f};
        if (valid) {
            va = *(const float4*)(ap + ks * 32);
            vb = *(const float4*)(ap + ks * 32 + 4);
        }
        short8 a;
        a[0] = f2bf(va.x); a[1] = f2bf(va.y); a[2] = f2bf(va.z); a[3] = f2bf(va.w);
        a[4] = f2bf(vb.x); a[5] = f2bf(vb.y); a[6] = f2bf(vb.z); a[7] = f2bf(vb.w);
#pragma unroll
        for (int nt = 0; nt < 8; ++nt) {
            short8 b = *(const short8*)&Wg[(((nt * 8 + ks) * 64) + lane) * 8];
            acc[nt] = __builtin_amdgcn_mfma_f32_16x16x32_bf16(a, b, acc[nt], 0, 0, 0);
        }
    }
    int quad = lane >> 4, cl = lane & 15;
#pragma unroll
    for (int r = 0; r < 4; ++r) {
        int gr = block_row + wv * 16 + quad * 4 + r;
        if (gr >= M) continue;
        float sc = rs_out[gr];
        int d0 = __builtin_amdgcn_cvt_pk_fp8_f32(acc[0][r] * sc, acc[1][r] * sc, 0, false);
        d0 = __builtin_amdgcn_cvt_pk_fp8_f32(acc[2][r] * sc, acc[3][r] * sc, d0, true);
        int d1 = __builtin_amdgcn_cvt_pk_fp8_f32(acc[4][r] * sc, acc[5][r] * sc, 0, false);
        d1 = __builtin_amdgcn_cvt_pk_fp8_f32(acc[6][r] * sc, acc[7][r] * sc, d1, true);
        uint2 dd = make_uint2((uint32_t)d0, (uint32_t)d1);
        *(uint2*)((char*)h1f + (size_t)gr * 128 + cl * 8) = dd;
    }
}

// ---------------- Fused SpMM1 + ReLU + GEMM2 (R3-proven block version) ----------------
// Block = 256 threads = 4 waves = 4 nodes (one node per wave).
// Gather: 16 lanes/edge x uint2; 16 edges per it-step = 4 independent loads in flight.
// Hot loop is mask-free (full steps) + one masked tail step. Accumulate in f32x2 (v_pk_add_f32).
// x1 rows parked in LDS (bf16, XOR-swizzled); 12 MFMAs -> h2f fp8, rows padded to 64 B.
__global__ __launch_bounds__(256) void k_spmm1f(const char* __restrict__ h1c, const int* __restrict__ rp,
                                                const int* __restrict__ col, const float* __restrict__ rs_in,
                                                const float* __restrict__ rs_out, const float* __restrict__ b1p,
                                                const short* __restrict__ Wg2,
                                                uint32_t* __restrict__ h2f, int N) {
    __shared__ uint32_t x1s[16 * 64];   // 16 rows x 256 B (only rows 0..3 written), 16B-granule XOR swizzle
    __shared__ uint32_t hs2[48];        // column-major fp8 staging: dword cc = bytes for nodes 0..3
    int t = threadIdx.x;
    int wv = t >> 6, lane = t & 63;
    int grp = lane >> 4, ql = lane & 15;
    int w_base = blockIdx.x * 4;
    int w = w_base + wv;

    float4 blo = *(const float4*)&b1p[ql * 8];
    float4 bhi = *(const float4*)&b1p[ql * 8 + 4];

    if (w < N) {
        int s = rp[w], e = rp[w + 1];
        f32x2 a0 = {0.f, 0.f}, a1 = {0.f, 0.f}, a2 = {0.f, 0.f}, a3 = {0.f, 0.f};
        int qoff = ql << 3;
        int i = s;
        while (i < e) {
            int cnt = min(64, e - i);
            int cl = (lane < cnt) ? lane : cnt - 1;
            int rof = col[i + cl] << 7;          // byte offset of 128B row
            int nfull = cnt & ~15;
            int it = 0;
            for (; it < nfull; it += 16) {       // mask-free full steps, 4 loads in flight
                int o0 = __shfl(rof, it + grp, 64) + qoff;
                int o1 = __shfl(rof, it + 4 + grp, 64) + qoff;
                int o2 = __shfl(rof, it + 8 + grp, 64) + qoff;
                int o3 = __shfl(rof, it + 12 + grp, 64) + qoff;
                uint2 u0 = *(const uint2*)(h1c + (uint32_t)o0);
                uint2 u1 = *(const uint2*)(h1c + (uint32_t)o1);
                uint2 u2 = *(const uint2*)(h1c + (uint32_t)o2);
                uint2 u3 = *(const uint2*)(h1c + (uint32_t)o3);
                a0 += __builtin_amdgcn_cvt_pk_f32_fp8(u0.x, false);
                a1 += __builtin_amdgcn_cvt_pk_f32_fp8(u0.x, true);
                a2 += __builtin_amdgcn_cvt_pk_f32_fp8(u0.y, false);
                a3 += __builtin_amdgcn_cvt_pk_f32_fp8(u0.y, true);
                a0 += __builtin_amdgcn_cvt_pk_f32_fp8(u1.x, false);
                a1 += __builtin_amdgcn_cvt_pk_f32_fp8(u1.x, true);
                a2 += __builtin_amdgcn_cvt_pk_f32_fp8(u1.y, false);
                a3 += __builtin_amdgcn_cvt_pk_f32_fp8(u1.y, true);
                a0 += __builtin_amdgcn_cvt_pk_f32_fp8(u2.x, false);
                a1 += __builtin_amdgcn_cvt_pk_f32_fp8(u2.x, true);
                a2 += __builtin_amdgcn_cvt_pk_f32_fp8(u2.y, false);
                a3 += __builtin_amdgcn_cvt_pk_f32_fp8(u2.y, true);
                a0 += __builtin_amdgcn_cvt_pk_f32_fp8(u3.x, false);
                a1 += __builtin_amdgcn_cvt_pk_f32_fp8(u3.x, true);
                a2 += __builtin_amdgcn_cvt_pk_f32_fp8(u3.y, false);
                a3 += __builtin_amdgcn_cvt_pk_f32_fp8(u3.y, true);
            }
            if (it < cnt) {                      // one masked tail step (<=15 edges)
                int e0 = it + grp;               // e0+12 <= 63 always
                int o0 = __shfl(rof, e0, 64) + qoff;
                int o1 = __shfl(rof, e0 + 4, 64) + qoff;
                int o2 = __shfl(rof, e0 + 8, 64) + qoff;
                int o3 = __shfl(rof, e0 + 12, 64) + qoff;
                float mv0 = (e0 < cnt) ? 1.f : 0.f;
                float mv1 = (e0 + 4 < cnt) ? 1.f : 0.f;
                float mv2 = (e0 + 8 < cnt) ? 1.f : 0.f;
                float mv3 = (e0 + 12 < cnt) ? 1.f : 0.f;
                f32x2 m0 = {mv0, mv0}, m1 = {mv1, mv1}, m2 = {mv2, mv2}, m3 = {mv3, mv3};
                uint2 u0 = *(const uint2*)(h1c + (uint32_t)o0);
                uint2 u1 = *(const uint2*)(h1c + (uint32_t)o1);
                uint2 u2 = *(const uint2*)(h1c + (uint32_t)o2);
                uint2 u3 = *(const uint2*)(h1c + (uint32_t)o3);
                a0 += __builtin_amdgcn_cvt_pk_f32_fp8(u0.x, false) * m0;
                a1 += __builtin_amdgcn_cvt_pk_f32_fp8(u0.x, true) * m0;
                a2 += __builtin_amdgcn_cvt_pk_f32_fp8(u0.y, false) * m0;
                a3 += __builtin_amdgcn_cvt_pk_f32_fp8(u0.y, true) * m0;
                a0 += __builtin_amdgcn_cvt_pk_f32_fp8(u1.x, false) * m1;
                a1 += __builtin_amdgcn_cvt_pk_f32_fp8(u1.x, true) * m1;
                a2 += __builtin_amdgcn_cvt_pk_f32_fp8(u1.y, false) * m1;
                a3 += __builtin_amdgcn_cvt_pk_f32_fp8(u1.y, true) * m1;
                a0 += __builtin_amdgcn_cvt_pk_f32_fp8(u2.x, false) * m2;
                a1 += __builtin_amdgcn_cvt_pk_f32_fp8(u2.x, true) * m2;
                a2 += __builtin_amdgcn_cvt_pk_f32_fp8(u2.y, false) * m2;
                a3 += __builtin_amdgcn_cvt_pk_f32_fp8(u2.y, true) * m2;
                a0 += __builtin_amdgcn_cvt_pk_f32_fp8(u3.x, false) * m3;
                a1 += __builtin_amdgcn_cvt_pk_f32_fp8(u3.x, true) * m3;
                a2 += __builtin_amdgcn_cvt_pk_f32_fp8(u3.y, false) * m3;
                a3 += __builtin_amdgcn_cvt_pk_f32_fp8(u3.y, true) * m3;
            }
            i += cnt;
        }
        float ac[8] = {a0.x, a0.y, a1.x, a1.y, a2.x, a2.y, a3.x, a3.y};
        // fold the 4 edge-groups (lane bits 4,5)
#pragma unroll
        for (int j = 0; j < 8; ++j) {
            ac[j] += __shfl_xor(ac[j], 16, 64);
            ac[j] += __shfl_xor(ac[j], 32, 64);
        }
        if (lane < 16) {
            float sc = rs_in[w];
            float f0, f1;
            uint32_t o0, o1, o2, o3;
            f0 = fmaxf(fmaf(ac[0], sc, blo.x), 0.f); f1 = fmaxf(fmaf(ac[1], sc, blo.y), 0.f);
            o0 = (uint32_t)(unsigned short)f2bf(f0) | ((uint32_t)(unsigned short)f2bf(f1) << 16);
            f0 = fmaxf(fmaf(ac[2], sc, blo.z), 0.f); f1 = fmaxf(fmaf(ac[3], sc, blo.w), 0.f);
            o1 = (uint32_t)(unsigned short)f2bf(f0) | ((uint32_t)(unsigned short)f2bf(f1) << 16);
            f0 = fmaxf(fmaf(ac[4], sc, bhi.x), 0.f); f1 = fmaxf(fmaf(ac[5], sc, bhi.y), 0.f);
            o2 = (uint32_t)(unsigned short)f2bf(f0) | ((uint32_t)(unsigned short)f2bf(f1) << 16);
            f0 = fmaxf(fmaf(ac[6], sc, bhi.z), 0.f); f1 = fmaxf(fmaf(ac[7], sc, bhi.w), 0.f);
            o3 = (uint32_t)(unsigned short)f2bf(f0) | ((uint32_t)(unsigned short)f2bf(f1) << 16);
            int woff = (wv * 256 + ql * 16) ^ ((wv & 7) << 4);
            *(uint4*)((char*)x1s + woff) = make_uint4(o0, o1, o2, o3);
        }
    }
    __syncthreads();
    int vr = min(4, N - w_base);
    if (wv < 3) {
        // W2 fragments loaded here (after edge phase) to keep hot-loop VGPR pressure low
        short8 wf0 = *(const short8*)&Wg2[((wv * 4 + 0) * 64 + lane) * 8];
        short8 wf1 = *(const short8*)&Wg2[((wv * 4 + 1) * 64 + lane) * 8];
        short8 wf2 = *(const short8*)&Wg2[((wv * 4 + 2) * 64 + lane) * 8];
        short8 wf3 = *(const short8*)&Wg2[((wv * 4 + 3) * 64 + lane) * 8];
        int row = lane & 15, kc = lane >> 4;
        int rbase = row * 256 + kc * 16;
        int swz = (row & 7) << 4;
        f32x4 c = {};
        c = __builtin_amdgcn_mfma_f32_16x16x32_bf16(*(short8*)((char*)x1s + ((rbase + 0) ^ swz)),   wf0, c, 0, 0, 0);
        c = __builtin_amdgcn_mfma_f32_16x16x32_bf16(*(short8*)((char*)x1s + ((rbase + 64) ^ swz)),  wf1, c, 0, 0, 0);
        c = __builtin_amdgcn_mfma_f32_16x16x32_bf16(*(short8*)((char*)x1s + ((rbase + 128) ^ swz)), wf2, c, 0, 0, 0);
        c = __builtin_amdgcn_mfma_f32_16x16x32_bf16(*(short8*)((char*)x1s + ((rbase + 192) ^ swz)), wf3, c, 0, 0, 0);
        int cc = wv * 16 + row;     // output column 0..47 (only <40 valid)
        if (cc < OUT_DIM && kc == 0) {   // C rows 0..3 live in kc==0 lanes
            float s0 = rs_out[w_base + 0];
            float s1 = (vr > 1) ? rs_out[w_base + 1] : 0.f;
            float s2 = (vr > 2) ? rs_out[w_base + 2] : 0.f;
            float s3 = (vr > 3) ? rs_out[w_base + 3] : 0.f;
            int pk = __builtin_amdgcn_cvt_pk_fp8_f32(c[0] * s0, c[1] * s1, 0, false);
            pk = __builtin_amdgcn_cvt_pk_fp8_f32(c[2] * s2, c[3] * s3, pk, true);
            hs2[cc] = (uint32_t)pk;      // banks 0..15 per wave: conflict-free
        }
    }
    __syncthreads();
    if (t < 64) {                        // assemble padded 64B rows: dword d of row `node`
        int node = t >> 4, d = t & 15;
        uint32_t v = 0;
        if (d < 10) {
            int sh = node * 8;
            uint32_t b0 = (hs2[4 * d + 0] >> sh) & 0xffu;
            uint32_t b1 = (hs2[4 * d + 1] >> sh) & 0xffu;
            uint32_t b2 = (hs2[4 * d + 2] >> sh) & 0xffu;
            uint32_t b3 = (hs2[4 * d + 3] >> sh) & 0xffu;
            v = b0 | (b1 << 8) | (b2 << 16) | (b3 << 24);
        }
        if (node < vr) h2f[(size_t)(w_base + node) * 16 + d] = v;
    }
}

// ---------------- SpMM2 (fp8, 64B-padded rows) + bias + log_softmax ----------------
// 8 lanes/edge x uint2; 32 edges per it-step = 4 independent loads in flight; mask-free hot loop.
__global__ __launch_bounds__(256) void k_spmm2(const char* __restrict__ h2c, const int* __restrict__ rp,
                                               const int* __restrict__ col, const float* __restrict__ rs_in,
                                               const float* __restrict__ b2, float* __restrict__ out, int n) {
    int w = (blockIdx.x * 256 + threadIdx.x) >> 6;
    int lane = threadIdx.x & 63;
    if (w >= n) return;
    int grp = lane >> 3, fl = lane & 7;       // fl: feature-byte group (fl<5 real, 5..7 pad=0)
    int qoff = fl << 3;
    int s = rp[w], e = rp[w + 1];
    f32x2 a0 = {0.f, 0.f}, a1 = {0.f, 0.f}, a2 = {0.f, 0.f}, a3 = {0.f, 0.f};
    int i = s;
    while (i < e) {
        int cnt = min(64, e - i);
        int cl = (lane < cnt) ? lane : cnt - 1;
        int rof = col[i + cl] << 6;           // byte offset of 64B row
        int nfull = cnt & ~31;
        int it = 0;
        for (; it < nfull; it += 32) {        // mask-free full steps
            int o0 = __shfl(rof, it + grp, 64) + qoff;
            int o1 = __shfl(rof, it + 8 + grp, 64) + qoff;
            int o2 = __shfl(rof, it + 16 + grp, 64) + qoff;
            int o3 = __shfl(rof, it + 24 + grp, 64) + qoff;
            uint2 u0 = *(const uint2*)(h2c + (uint32_t)o0);
            uint2 u1 = *(const uint2*)(h2c + (uint32_t)o1);
            uint2 u2 = *(const uint2*)(h2c + (uint32_t)o2);
            uint2 u3 = *(const uint2*)(h2c + (uint32_t)o3);
            a0 += __builtin_amdgcn_cvt_pk_f32_fp8(u0.x, false);
            a1 += __builtin_amdgcn_cvt_pk_f32_fp8(u0.x, true);
            a2 += __builtin_amdgcn_cvt_pk_f32_fp8(u0.y, false);
            a3 += __builtin_amdgcn_cvt_pk_f32_fp8(u0.y, true);
            a0 += __builtin_amdgcn_cvt_pk_f32_fp8(u1.x, false);
            a1 += __builtin_amdgcn_cvt_pk_f32_fp8(u1.x, true);
            a2 += __builtin_amdgcn_cvt_pk_f32_fp8(u1.y, false);
            a3 += __builtin_amdgcn_cvt_pk_f32_fp8(u1.y, true);
            a0 += __builtin_amdgcn_cvt_pk_f32_fp8(u2.x, false);
            a1 += __builtin_amdgcn_cvt_pk_f32_fp8(u2.x, true);
            a2 += __builtin_amdgcn_cvt_pk_f32_fp8(u2.y, false);
            a3 += __builtin_amdgcn_cvt_pk_f32_fp8(u2.y, true);
            a0 += __builtin_amdgcn_cvt_pk_f32_fp8(u3.x, false);
            a1 += __builtin_amdgcn_cvt_pk_f32_fp8(u3.x, true);
            a2 += __builtin_amdgcn_cvt_pk_f32_fp8(u3.y, false);
            a3 += __builtin_amdgcn_cvt_pk_f32_fp8(u3.y, true);
        }
        if (it < cnt) {                       // one masked tail step (<=31 edges)
            int e0 = it + grp;                // e0+24 <= 63 always
            int o0 = __shfl(rof, e0, 64) + qoff;
            int o1 = __shfl(rof, e0 + 8, 64) + qoff;
            int o2 = __shfl(rof, e0 + 16, 64) + qoff;
            int o3 = __shfl(rof, e0 + 24, 64) + qoff;
            float mv0 = (e0 < cnt) ? 1.f : 0.f;
            float mv1 = (e0 + 8 < cnt) ? 1.f : 0.f;
            float mv2 = (e0 + 16 < cnt) ? 1.f : 0.f;
            float mv3 = (e0 + 24 < cnt) ? 1.f : 0.f;
            f32x2 m0 = {mv0, mv0}, m1 = {mv1, mv1}, m2 = {mv2, mv2}, m3 = {mv3, mv3};
            uint2 u0 = *(const uint2*)(h2c + (uint32_t)o0);
            uint2 u1 = *(const uint2*)(h2c + (uint32_t)o1);
            uint2 u2 = *(const uint2*)(h2c + (uint32_t)o2);
            uint2 u3 = *(const uint2*)(h2c + (uint32_t)o3);
            a0 += __builtin_amdgcn_cvt_pk_f32_fp8(u0.x, false) * m0;
            a1 += __builtin_amdgcn_cvt_pk_f32_fp8(u0.x, true) * m0;
            a2 += __builtin_amdgcn_cvt_pk_f32_fp8(u0.y, false) * m0;
            a3 += __builtin_amdgcn_cvt_pk_f32_fp8(u0.y, true) * m0;
            a0 += __builtin_amdgcn_cvt_pk_f32_fp8(u1.x, false) * m1;
            a1 += __builtin_amdgcn_cvt_pk_f32_fp8(u1.x, true) * m1;
            a2 += __builtin_amdgcn_cvt_pk_f32_fp8(u1.y, false) * m1;
            a3 += __builtin_amdgcn_cvt_pk_f32_fp8(u1.y, true) * m1;
            a0 += __builtin_amdgcn_cvt_pk_f32_fp8(u2.x, false) * m2;
            a1 += __builtin_amdgcn_cvt_pk_f32_fp8(u2.x, true) * m2;
            a2 += __builtin_amdgcn_cvt_pk_f32_fp8(u2.y, false) * m2;
            a3 += __builtin_amdgcn_cvt_pk_f32_fp8(u2.y, true) * m2;
            a0 += __builtin_amdgcn_cvt_pk_f32_fp8(u3.x, false) * m3;
            a1 += __builtin_amdgcn_cvt_pk_f32_fp8(u3.x, true) * m3;
            a2 += __builtin_amdgcn_cvt_pk_f32_fp8(u3.y, false) * m3;
            a3 += __builtin_amdgcn_cvt_pk_f32_fp8(u3.y, true) * m3;
        }
        i += cnt;
    }
    float ac[8] = {a0.x, a0.y, a1.x, a1.y, a2.x, a2.y, a3.x, a3.y};
    // fold 8 edge-groups (lane bits 3,4,5)
#pragma unroll
    for (int j = 0; j < 8; ++j) {
        ac[j] += __shfl_xor(ac[j], 8, 64);
        ac[j] += __shfl_xor(ac[j], 16, 64);
        ac[j] += __shfl_xor(ac[j], 32, 64);
    }
    bool act = lane < 5;
    float sc = rs_in[w];
    int bb = (fl < 5) ? fl * 8 : 0;           // guard b2 OOB for pad lanes
    float val[8];
#pragma unroll
    for (int j = 0; j < 8; ++j)
        val[j] = fmaf(ac[j], sc, b2[bb + j]);
    float pm = -INFINITY;
    if (act) {
        pm = val[0];
#pragma unroll
        for (int j = 1; j < 8; ++j) pm = fmaxf(pm, val[j]);
    }
    pm = fmaxf(pm, __shfl_xor(pm, 4, 8));
    pm = fmaxf(pm, __shfl_xor(pm, 2, 8));
    pm = fmaxf(pm, __shfl_xor(pm, 1, 8));
    float ex = 0.f;
    if (act) {
#pragma unroll
        for (int j = 0; j < 8; ++j) ex += expf(val[j] - pm);
    }
    ex += __shfl_xor(ex, 4, 8);
    ex += __shfl_xor(ex, 2, 8);
    ex += __shfl_xor(ex, 1, 8);
    if (act) {
        float l = pm + logf(ex);
        float4 o0 = {val[0] - l, val[1] - l, val[2] - l, val[3] - l};
        float4 o1 = {val[4] - l, val[5] - l, val[6] - l, val[7] - l};
        float* op = out + (size_t)w * OUT_DIM + lane * 8;
        *(float4*)op = o0;
        *(float4*)(op + 4) = o1;
    }
}

// ---------------- launch ----------------

extern "C" void kernel_launch(void* const* d_in, const int* in_sizes, int n_in,
                              void* d_out, int out_size, void* d_ws, size_t ws_size,
                              hipStream_t stream) {
    const int N = in_sizes[0] / IN_DIM;
    const int E = in_sizes[5];
    const float* h  = (const float*)d_in[0];
    const float* W1 = (const float*)d_in[1];
    const float* b1 = (const float*)d_in[2];
    const float* W2 = (const float*)d_in[3];
    const float* b2 = (const float*)d_in[4];
    const int* src  = (const int*)d_in[5];
    const int* dst  = (const int*)d_in[6];
    float* out = (float*)d_out;

    const int NBINS  = (N + BIN_SIZE - 1) >> BIN_SHIFT;   // 98
    const int NCHUNK = (E + CHUNK - 1) / CHUNK;           // 782

    char* w = (char*)d_ws;
    size_t off = 0;
    auto alloc = [&](size_t bytes) -> void* {
        void* p = w + off;
        off += (bytes + 255) & ~(size_t)255;
        return p;
    };
    int* deg_in   = (int*)alloc((size_t)N * 4);
    int* deg_out  = (int*)alloc((size_t)N * 4);
    int* row_ptr  = (int*)alloc((size_t)(N + 1) * 4);
    int* cursor   = (int*)alloc((size_t)N * 4);
    int* bsum     = (int*)alloc(1024 * 4);
    float* rs_out = (float*)alloc((size_t)N * 4);
    float* rs_in  = (float*)alloc((size_t)N * 4);
    int* col      = (int*)alloc((size_t)E * 4);
    int* bboD     = (int*)alloc((size_t)NCHUNK * (NBINS + 1) * 4);
    int* bboS     = (int*)alloc((size_t)NCHUNK * (NBINS + 1) * 4);
    short* Wg     = (short*)alloc((size_t)8 * 8 * 64 * 8 * 2);    // 64 KB
    short* Wg2    = (short*)alloc((size_t)3 * 4 * 64 * 8 * 2);    // 12 KB
    float* b1p    = (float*)alloc((size_t)HID * 4);
    int* hsave    = (int*)alloc((size_t)NBINS * GSPLIT * BIN_SIZE * 4);   // 3.2 MB
    uint32_t* stD = (uint32_t*)alloc((size_t)E * 4);              // 12.8 MB
    unsigned short* stS = (unsigned short*)alloc((size_t)E * 2);  // 6.4 MB
    uint32_t* h1f = (uint32_t*)alloc((size_t)N * HID);            // fp8 [N][128], 12.8 MB (own buffer: col+gemm1 overlap)
    uint32_t* h2f = (uint32_t*)alloc((size_t)N * 64);             // fp8 [N][64] (40 real + 24 pad), 6.4 MB

    int gN = (N + 255) / 256;
    int NB = (N + 1023) / 1024;
    int Z = (N + 3) / 4;
    int setup_units = 8192 + 3 * 4 * 64 * 8 + HID + 2 * Z;
    int setupBlocks = (setup_units + 255) / 256;
    int colBlocks = NBINS * GSPLIT;

    k_init<<<setupBlocks + NCHUNK, 256, 0, stream>>>(W1, W2, b1, Wg, Wg2, b1p, deg_in, deg_out, Z,
                                                     src, dst, stD, stS, bboD, bboS, E, NBINS, setupBlocks);
    k_deg<<<dim3(NBINS, GSPLIT, 2), 256, 0, stream>>>(stD, bboD, stS, bboS, deg_in, deg_out, hsave, NCHUNK, NBINS);
    k_scan1<<<NB, 256, 0, stream>>>(deg_in, row_ptr, bsum, rs_in, N);
    k_scan3<<<gN, 256, 0, stream>>>(row_ptr, bsum, cursor, deg_out, rs_out, N, E, NB);
    k_colgemm1<<<colBlocks + (N + 63) / 64, 256, 0, stream>>>(stD, bboD, hsave, cursor, col, NCHUNK, NBINS,
                                                              colBlocks, h, Wg, rs_out, h1f, N);
    k_spmm1f<<<(N + 3) / 4, 256, 0, stream>>>((const char*)h1f, row_ptr, col, rs_in, rs_out, b1p, Wg2, h2f, N);
    k_spmm2<<<(N + 3) / 4, 256, 0, stream>>>((const char*)h2f, row_ptr, col, rs_in, b2, out, N);
}

// Round 11
// 397.351 us; speedup vs baseline: 1.1575x; 1.0255x over previous
//
#include <hip/hip_runtime.h>
#include <hip/hip_bf16.h>
#include <cstddef>
#include <cstdint>

#define IN_DIM 256
#define HID 128
#define OUT_DIM 40

#define CHUNK 4096      // edges per binscatter block (LDS-staged counting sort)
#define BIN_SHIFT 10    // 1024 nodes per bin
#define BIN_SIZE 1024
#define MAXB 128        // >= NBINS+1
#define GSPLIT 8        // blocks per bin for deg/col kernels

typedef __attribute__((ext_vector_type(8))) short short8;
typedef __attribute__((ext_vector_type(4))) float f32x4;
typedef __attribute__((ext_vector_type(2))) float f32x2;

__device__ inline short f2bf(float f) {
    __hip_bfloat16 b = __float2bfloat16(f);   // RNE
    return __builtin_bit_cast(short, b);
}
__device__ inline float bf2f(unsigned short u) {
    unsigned int v = (unsigned int)u << 16;
    return __builtin_bit_cast(float, v);
}
// feature permutation for h1/x1 storage: slot p holds feature (p>>3) + 16*(p&7).
__device__ inline int permf(int p) { return (p >> 3) + 16 * (p & 7); }

// ---------------- merged init: [0,setupBlocks) = W repacks + deg zeroing; rest = binscatter ----------------
// Binscatter: LDS-staged chunk-private counting sort (avoids ~9x partial-line write amplification
// of scattered 4B/2B global stores — measured R5: WRITE_SIZE 113 MB for 12.5 MB payload).
__global__ __launch_bounds__(256) void k_init(const float* __restrict__ W1, const float* __restrict__ W2,
                                              const float* __restrict__ b1, short* __restrict__ Wg,
                                              short* __restrict__ Wg2, float* __restrict__ b1p,
                                              int* __restrict__ deg_in, int* __restrict__ deg_out, int Z,
                                              const int* __restrict__ src, const int* __restrict__ dst,
                                              uint32_t* __restrict__ stD, unsigned short* __restrict__ stS,
                                              int* __restrict__ bboD, int* __restrict__ bboS,
                                              int E, int NBINS, int setupBlocks) {
    __shared__ __align__(16) uint32_t sgD[CHUNK];         // 16 KB
    __shared__ __align__(16) unsigned short sgS[CHUNK];   // 8 KB
    __shared__ int hD[MAXB], hS[MAXB], sd[MAXB];
    int t = threadIdx.x;
    if (blockIdx.x < setupBlocks) {
        int flat = blockIdx.x * 256 + t;
        if (flat < 8192) {                        // W1: fp32 [256][128] -> bf16 fragments [nt][ks][lane][8]
            int k = flat >> 5;
            int n0 = (flat & 31) * 4;
            float4 v = *(const float4*)(W1 + (size_t)k * HID + n0);
            int ks = k >> 5, quad = (k >> 3) & 3, j = k & 7;
            float vv[4] = {v.x, v.y, v.z, v.w};
#pragma unroll
            for (int e = 0; e < 4; ++e) {
                int n = n0 + e;
                int nt = n >> 4;
                int ln = (n & 15) | (quad << 4);
                Wg[(((nt * 8 + ks) * 64) + ln) * 8 + j] = f2bf(vv[e]);
            }
            return;
        }
        flat -= 8192;
        if (flat < 3 * 4 * 64 * 8) {              // W2: fp32 [128][40] -> bf16 B-fragments (pad cols 40->48)
            int f = flat >> 9;
            int ln = (flat >> 3) & 63;
            int j = flat & 7;
            int nt = f >> 2, ks = f & 3;
            int q = ks * 32 + (ln >> 4) * 8 + j;  // x1 slot (permuted feature index)
            int c = nt * 16 + (ln & 15);          // output col
            float v = (c < OUT_DIM) ? W2[(size_t)permf(q) * OUT_DIM + c] : 0.f;
            Wg2[flat] = f2bf(v);
            return;
        }
        flat -= 3 * 4 * 64 * 8;
        if (flat < HID) { b1p[flat] = b1[permf(flat)]; return; }
        flat -= HID;
        if (flat < Z) { *(int4*)(deg_in + flat * 4) = make_int4(0, 0, 0, 0); return; }
        flat -= Z;
        if (flat < Z) { *(int4*)(deg_out + flat * 4) = make_int4(0, 0, 0, 0); }
        return;
    }
    // ---- binscatter ----
    int j = blockIdx.x - setupBlocks;
    int base = j * CHUNK;
    int nE = min(CHUNK, E - base);
    int NB1 = NBINS + 1;
    for (int i = t; i < MAXB; i += 256) { hD[i] = 0; hS[i] = 0; }
    __syncthreads();
    for (int i = t; i < nE; i += 256) {
        atomicAdd(&hD[dst[base + i] >> BIN_SHIFT], 1);
        atomicAdd(&hS[src[base + i] >> BIN_SHIFT], 1);
    }
    __syncthreads();
    // scan D
    if (t < MAXB) sd[t] = hD[t];
    __syncthreads();
    for (int off = 1; off < MAXB; off <<= 1) {
        int x = 0;
        if (t < MAXB && t >= off) x = sd[t - off];
        __syncthreads();
        if (t < MAXB) sd[t] += x;
        __syncthreads();
    }
    if (t < MAXB) {
        int h = hD[t];
        int c = sd[t] - h;
        hD[t] = c;                                  // hD becomes cursor
        if (t < NBINS) bboD[(size_t)j * NB1 + t] = c;
    }
    if (t == NBINS) bboD[(size_t)j * NB1 + NBINS] = nE;
    __syncthreads();
    // scan S
    if (t < MAXB) sd[t] = hS[t];
    __syncthreads();
    for (int off = 1; off < MAXB; off <<= 1) {
        int x = 0;
        if (t < MAXB && t >= off) x = sd[t - off];
        __syncthreads();
        if (t < MAXB) sd[t] += x;
        __syncthreads();
    }
    if (t < MAXB) {
        int h = hS[t];
        int c = sd[t] - h;
        hS[t] = c;                                  // hS becomes cursor
        if (t < NBINS) bboS[(size_t)j * NB1 + t] = c;
    }
    if (t == NBINS) bboS[(size_t)j * NB1 + NBINS] = nE;
    __syncthreads();
    // scatter into LDS staging
    for (int i = t; i < nE; i += 256) {
        int s = src[base + i], d = dst[base + i];
        int pD = atomicAdd(&hD[d >> BIN_SHIFT], 1);
        sgD[pD] = ((uint32_t)(d & (BIN_SIZE - 1)) << 17) | (uint32_t)s;
        int pS = atomicAdd(&hS[s >> BIN_SHIFT], 1);
        sgS[pS] = (unsigned short)(s & (BIN_SIZE - 1));
    }
    __syncthreads();
    // coalesced flush
    int nh = nE >> 1;
    uint2* dD = (uint2*)(stD + base);
    const uint2* sD = (const uint2*)sgD;
    for (int i = t; i < nh; i += 256) dD[i] = sD[i];
    uint32_t* dS = (uint32_t*)(stS + base);
    const uint32_t* sS = (const uint32_t*)sgS;
    for (int i = t; i < nh; i += 256) dS[i] = sS[i];
    if ((nE & 1) && t == 0) { stD[base + nE - 1] = sgD[nE - 1]; stS[base + nE - 1] = sgS[nE - 1]; }
}

// ---------------- merged degree kernel: z==0 dst (+hsave persist), z==1 src ----------------
// 4 chunk-segments in flight per wave iteration (latency chains overlap).
__global__ __launch_bounds__(256) void k_deg(const uint32_t* __restrict__ stD, const int* __restrict__ bboD,
                                             const unsigned short* __restrict__ stS, const int* __restrict__ bboS,
                                             int* __restrict__ deg_in, int* __restrict__ deg_out,
                                             int* __restrict__ hsave, int nchunk, int NBINS) {
    __shared__ int hist[BIN_SIZE];
    int b = blockIdx.x, g = blockIdx.y, t = threadIdx.x;
    int wv = t >> 6, lane = t & 63;
    int NB1 = NBINS + 1;
    for (int i = t; i < BIN_SIZE; i += 256) hist[i] = 0;
    __syncthreads();
    int base = b << BIN_SHIFT;
    if (blockIdx.z == 0) {
        for (int jj = g * 4 + wv; jj < nchunk; jj += 128) {
            int s[4], e[4];
            uint32_t v[4];
            bool av[4];
#pragma unroll
            for (int q = 0; q < 4; ++q) {
                int j = jj + q * 32;
                bool jv = j < nchunk;
                s[q] = jv ? bboD[(size_t)j * NB1 + b] : 0;
                e[q] = jv ? bboD[(size_t)j * NB1 + b + 1] : 0;
            }
#pragma unroll
            for (int q = 0; q < 4; ++q) {
                av[q] = s[q] + lane < e[q];
                v[q] = av[q] ? stD[(size_t)(jj + q * 32) * CHUNK + s[q] + lane] : 0u;
            }
#pragma unroll
            for (int q = 0; q < 4; ++q)
                if (av[q]) atomicAdd(&hist[v[q] >> 17], 1);
#pragma unroll
            for (int q = 0; q < 4; ++q) {
                int j = jj + q * 32;
                for (int i = s[q] + lane + 64; i < e[q]; i += 64)
                    atomicAdd(&hist[stD[(size_t)j * CHUNK + i] >> 17], 1);
            }
        }
        __syncthreads();
        int* hp = hsave + ((size_t)(b * GSPLIT + g) << BIN_SHIFT);
        for (int i = t; i < BIN_SIZE; i += 256) {
            int v = hist[i];
            hp[i] = v;
            if (v) atomicAdd(&deg_in[base + i], v);
        }
    } else {
        for (int jj = g * 4 + wv; jj < nchunk; jj += 128) {
            int s[4], e[4];
            unsigned short v[4];
            bool av[4];
#pragma unroll
            for (int q = 0; q < 4; ++q) {
                int j = jj + q * 32;
                bool jv = j < nchunk;
                s[q] = jv ? bboS[(size_t)j * NB1 + b] : 0;
                e[q] = jv ? bboS[(size_t)j * NB1 + b + 1] : 0;
            }
#pragma unroll
            for (int q = 0; q < 4; ++q) {
                av[q] = s[q] + lane < e[q];
                v[q] = av[q] ? stS[(size_t)(jj + q * 32) * CHUNK + s[q] + lane] : (unsigned short)0;
            }
#pragma unroll
            for (int q = 0; q < 4; ++q)
                if (av[q]) atomicAdd(&hist[v[q]], 1);
#pragma unroll
            for (int q = 0; q < 4; ++q) {
                int j = jj + q * 32;
                for (int i = s[q] + lane + 64; i < e[q]; i += 64)
                    atomicAdd(&hist[stS[(size_t)j * CHUNK + i]], 1);
            }
        }
        __syncthreads();
        for (int i = t; i < BIN_SIZE; i += 256) {
            int v = hist[i];
            if (v) atomicAdd(&deg_out[base + i], v);
        }
    }
}

__global__ __launch_bounds__(256) void k_scan1(const int* __restrict__ deg, int* __restrict__ out,
                                               int* __restrict__ bsum, float* __restrict__ rs_in, int n) {
    __shared__ int sd[256];
    int t = threadIdx.x, b = blockIdx.x;
    int base = b * 1024 + t * 4;
    int v0 = 0, v1 = 0, v2 = 0, v3 = 0;
    if (base + 0 < n) v0 = deg[base + 0];
    if (base + 1 < n) v1 = deg[base + 1];
    if (base + 2 < n) v2 = deg[base + 2];
    if (base + 3 < n) v3 = deg[base + 3];
    if (base + 0 < n) rs_in[base + 0] = rsqrtf((float)max(v0, 1));
    if (base + 1 < n) rs_in[base + 1] = rsqrtf((float)max(v1, 1));
    if (base + 2 < n) rs_in[base + 2] = rsqrtf((float)max(v2, 1));
    if (base + 3 < n) rs_in[base + 3] = rsqrtf((float)max(v3, 1));
    int ts = v0 + v1 + v2 + v3;
    sd[t] = ts;
    __syncthreads();
    for (int off = 1; off < 256; off <<= 1) {
        int x = 0;
        if (t >= off) x = sd[t - off];
        __syncthreads();
        sd[t] += x;
        __syncthreads();
    }
    int excl = sd[t] - ts;
    if (base + 0 < n) out[base + 0] = excl;
    if (base + 1 < n) out[base + 1] = excl + v0;
    if (base + 2 < n) out[base + 2] = excl + v0 + v1;
    if (base + 3 < n) out[base + 3] = excl + v0 + v1 + v2;
    if (t == 255) bsum[b] = sd[255];
}

// scan3 with the (tiny) bsum scan done redundantly per block (removes the 1-block scan2 launch).
// Requires NB <= 128 (N <= 131072; here N = 100000 -> NB = 98).
__global__ __launch_bounds__(256) void k_scan3(int* __restrict__ row_ptr, const int* __restrict__ bsum,
                                               int* __restrict__ cursor, const int* __restrict__ deg_out,
                                               float* __restrict__ rs_out, int n, int E, int NB) {
    __shared__ int sb[128];
    int t = threadIdx.x;
    if (t < 128) sb[t] = (t < NB) ? bsum[t] : 0;
    __syncthreads();
    for (int off = 1; off < 128; off <<= 1) {
        int x = 0;
        if (t < 128 && t >= off) x = sb[t - off];
        __syncthreads();
        if (t < 128) sb[t] += x;
        __syncthreads();
    }
    int i = blockIdx.x * 256 + threadIdx.x;
    if (i < n) {
        int blk = i >> 10;
        int add = (blk > 0) ? sb[blk - 1] : 0;     // exclusive prefix of block sums
        int v = row_ptr[i] + add;
        row_ptr[i] = v;
        cursor[i] = v;
        rs_out[i] = rsqrtf((float)max(deg_out[i], 1));
    }
    if (i == 0) row_ptr[n] = E;
}

// ---------------- merged col + GEMM1 (one launch; complementary pipes overlap) ----------------
// [0, colBlocks): col scatter, XCD-AFFINE mapping: all GSPLIT worker blocks of bin b get
// blockIdx == b (mod 8), so (with round-robin workgroup->XCD dispatch) a bin's 128KB col window
// is written through ONE XCD's L2 -> full-line accumulation instead of 8 XCDs each writing
// partial sectors (R10 measured 101 MB WRITE for ~26 MB payload; R9 proved single-owner drops it
// to ~77 MB total). Mapping is a perf heuristic only — any XCD assignment stays correct.
// 4 chunk-segments in flight per wave iteration.
// [colBlocks, ...): GEMM1 — LDS-free (R8): lane's MFMA A-fragment = 8 consecutive k of one row,
// loaded straight from global as 2x float4.
__global__ __launch_bounds__(256) void k_colgemm1(const uint32_t* __restrict__ stD, const int* __restrict__ bboD,
                                                  const int* __restrict__ hsave, int* __restrict__ cursor,
                                                  int* __restrict__ col, int nchunk, int NBINS, int colBlocks,
                                                  const float* __restrict__ A, const short* __restrict__ Wg,
                                                  const float* __restrict__ rs_out, uint32_t* __restrict__ h1f,
                                                  int M) {
    __shared__ int hist[BIN_SIZE];            // col histogram (4 KB) — only LDS in this kernel
    int t = threadIdx.x;
    if (blockIdx.x < colBlocks) {
        int cb = blockIdx.x;
        int x = cb & 7, y = cb >> 3;
        int b = x + 8 * (y / GSPLIT);         // all g-blocks of bin b share blockIdx%8 == b%8
        int g = y % GSPLIT;
        if (b >= NBINS) return;               // padded blocks (b beyond last bin)
        int wv = t >> 6, lane = t & 63;
        int NB1 = NBINS + 1;
        int base = b << BIN_SHIFT;
        const int* hp = hsave + ((size_t)(b * GSPLIT + g) << BIN_SHIFT);
        for (int i = t; i < BIN_SIZE; i += 256) {
            int v = hp[i];
            hist[i] = v ? atomicAdd(&cursor[base + i], v) : 0;
        }
        __syncthreads();
        for (int jj = g * 4 + wv; jj < nchunk; jj += 128) {
            int s[4], e[4];
            uint32_t v[4];
            bool av[4];
#pragma unroll
            for (int q = 0; q < 4; ++q) {
                int j = jj + q * 32;
                bool jv = j < nchunk;
                s[q] = jv ? bboD[(size_t)j * NB1 + b] : 0;
                e[q] = jv ? bboD[(size_t)j * NB1 + b + 1] : 0;
            }
#pragma unroll
            for (int q = 0; q < 4; ++q) {
                av[q] = s[q] + lane < e[q];
                v[q] = av[q] ? stD[(size_t)(jj + q * 32) * CHUNK + s[q] + lane] : 0u;
            }
#pragma unroll
            for (int q = 0; q < 4; ++q) {
                if (av[q]) {
                    int pos = atomicAdd(&hist[v[q] >> 17], 1);
                    col[pos] = (int)(v[q] & 0x1FFFFu);
                }
            }
#pragma unroll
            for (int q = 0; q < 4; ++q) {
                int j = jj + q * 32;
                for (int i = s[q] + lane + 64; i < e[q]; i += 64) {
                    uint32_t vv = stD[(size_t)j * CHUNK + i];
                    int pos = atomicAdd(&hist[vv >> 17], 1);
                    col[pos] = (int)(vv & 0x1FFFFu);
                }
            }
        }
        return;
    }
    // ---- GEMM1 (LDS-free) ----
    int lane = t & 63, wv = t >> 6;
    int block_row = (blockIdx.x - colBlocks) * 64;
    int row = block_row + wv * 16 + (lane & 15);
    bool valid = row < M;
    const float* ap = A + (size_t)row * IN_DIM + (lane >> 4) * 8;
    f32x4 acc[8] = {};
#pragma unroll
    for (int ks = 0; ks < 8; ++ks) {
        float4 va = {0.f, 0.f, 0.f, 0.f}, vb = {0.f, 0.f, 0.f, 0.f};
        if (valid) {
            va = *(const float4*)(ap + ks * 32);
            vb = *(const float4*)(ap + ks * 32 + 4);
        }
        short8 a;
        a[0] = f2bf(va.x); a[1] = f2bf(va.y); a[2] = f2bf(va.z); a[3] = f2bf(va.w);
        a[4] = f2bf(vb.x); a[5] = f2bf(vb.y); a[6] = f2bf(vb.z); a[7] = f2bf(vb.w);
#pragma unroll
        for (int nt = 0; nt < 8; ++nt) {
            short8 b = *(const short8*)&Wg[(((nt * 8 + ks) * 64) + lane) * 8];
            acc[nt] = __builtin_amdgcn_mfma_f32_16x16x32_bf16(a, b, acc[nt], 0, 0, 0);
        }
    }
    int quad = lane >> 4, cl = lane & 15;
#pragma unroll
    for (int r = 0; r < 4; ++r) {
        int gr = block_row + wv * 16 + quad * 4 + r;
        if (gr >= M) continue;
        float sc = rs_out[gr];
        int d0 = __builtin_amdgcn_cvt_pk_fp8_f32(acc[0][r] * sc, acc[1][r] * sc, 0, false);
        d0 = __builtin_amdgcn_cvt_pk_fp8_f32(acc[2][r] * sc, acc[3][r] * sc, d0, true);
        int d1 = __builtin_amdgcn_cvt_pk_fp8_f32(acc[4][r] * sc, acc[5][r] * sc, 0, false);
        d1 = __builtin_amdgcn_cvt_pk_fp8_f32(acc[6][r] * sc, acc[7][r] * sc, d1, true);
        uint2 dd = make_uint2((uint32_t)d0, (uint32_t)d1);
        *(uint2*)((char*)h1f + (size_t)gr * 128 + cl * 8) = dd;
    }
}

// ---------------- Fused SpMM1 + ReLU + GEMM2 (R3-proven block version) ----------------
// Block = 256 threads = 4 waves = 4 nodes (one node per wave).
// Gather: 16 lanes/edge x uint2; 16 edges per it-step = 4 independent loads in flight.
// Hot loop is mask-free (full steps) + one masked tail step. Accumulate in f32x2 (v_pk_add_f32).
// x1 rows parked in LDS (bf16, XOR-swizzled); 12 MFMAs -> h2f fp8, rows padded to 64 B.
__global__ __launch_bounds__(256) void k_spmm1f(const char* __restrict__ h1c, const int* __restrict__ rp,
                                                const int* __restrict__ col, const float* __restrict__ rs_in,
                                                const float* __restrict__ rs_out, const float* __restrict__ b1p,
                                                const short* __restrict__ Wg2,
                                                uint32_t* __restrict__ h2f, int N) {
    __shared__ uint32_t x1s[16 * 64];   // 16 rows x 256 B (only rows 0..3 written), 16B-granule XOR swizzle
    __shared__ uint32_t hs2[48];        // column-major fp8 staging: dword cc = bytes for nodes 0..3
    int t = threadIdx.x;
    int wv = t >> 6, lane = t & 63;
    int grp = lane >> 4, ql = lane & 15;
    int w_base = blockIdx.x * 4;
    int w = w_base + wv;

    float4 blo = *(const float4*)&b1p[ql * 8];
    float4 bhi = *(const float4*)&b1p[ql * 8 + 4];

    if (w < N) {
        int s = rp[w], e = rp[w + 1];
        f32x2 a0 = {0.f, 0.f}, a1 = {0.f, 0.f}, a2 = {0.f, 0.f}, a3 = {0.f, 0.f};
        int qoff = ql << 3;
        int i = s;
        while (i < e) {
            int cnt = min(64, e - i);
            int cl = (lane < cnt) ? lane : cnt - 1;
            int rof = col[i + cl] << 7;          // byte offset of 128B row
            int nfull = cnt & ~15;
            int it = 0;
            for (; it < nfull; it += 16) {       // mask-free full steps, 4 loads in flight
                int o0 = __shfl(rof, it + grp, 64) + qoff;
                int o1 = __shfl(rof, it + 4 + grp, 64) + qoff;
                int o2 = __shfl(rof, it + 8 + grp, 64) + qoff;
                int o3 = __shfl(rof, it + 12 + grp, 64) + qoff;
                uint2 u0 = *(const uint2*)(h1c + (uint32_t)o0);
                uint2 u1 = *(const uint2*)(h1c + (uint32_t)o1);
                uint2 u2 = *(const uint2*)(h1c + (uint32_t)o2);
                uint2 u3 = *(const uint2*)(h1c + (uint32_t)o3);
                a0 += __builtin_amdgcn_cvt_pk_f32_fp8(u0.x, false);
                a1 += __builtin_amdgcn_cvt_pk_f32_fp8(u0.x, true);
                a2 += __builtin_amdgcn_cvt_pk_f32_fp8(u0.y, false);
                a3 += __builtin_amdgcn_cvt_pk_f32_fp8(u0.y, true);
                a0 += __builtin_amdgcn_cvt_pk_f32_fp8(u1.x, false);
                a1 += __builtin_amdgcn_cvt_pk_f32_fp8(u1.x, true);
                a2 += __builtin_amdgcn_cvt_pk_f32_fp8(u1.y, false);
                a3 += __builtin_amdgcn_cvt_pk_f32_fp8(u1.y, true);
                a0 += __builtin_amdgcn_cvt_pk_f32_fp8(u2.x, false);
                a1 += __builtin_amdgcn_cvt_pk_f32_fp8(u2.x, true);
                a2 += __builtin_amdgcn_cvt_pk_f32_fp8(u2.y, false);
                a3 += __builtin_amdgcn_cvt_pk_f32_fp8(u2.y, true);
                a0 += __builtin_amdgcn_cvt_pk_f32_fp8(u3.x, false);
                a1 += __builtin_amdgcn_cvt_pk_f32_fp8(u3.x, true);
                a2 += __builtin_amdgcn_cvt_pk_f32_fp8(u3.y, false);
                a3 += __builtin_amdgcn_cvt_pk_f32_fp8(u3.y, true);
            }
            if (it < cnt) {                      // one masked tail step (<=15 edges)
                int e0 = it + grp;               // e0+12 <= 63 always
                int o0 = __shfl(rof, e0, 64) + qoff;
                int o1 = __shfl(rof, e0 + 4, 64) + qoff;
                int o2 = __shfl(rof, e0 + 8, 64) + qoff;
                int o3 = __shfl(rof, e0 + 12, 64) + qoff;
                float mv0 = (e0 < cnt) ? 1.f : 0.f;
                float mv1 = (e0 + 4 < cnt) ? 1.f : 0.f;
                float mv2 = (e0 + 8 < cnt) ? 1.f : 0.f;
                float mv3 = (e0 + 12 < cnt) ? 1.f : 0.f;
                f32x2 m0 = {mv0, mv0}, m1 = {mv1, mv1}, m2 = {mv2, mv2}, m3 = {mv3, mv3};
                uint2 u0 = *(const uint2*)(h1c + (uint32_t)o0);
                uint2 u1 = *(const uint2*)(h1c + (uint32_t)o1);
                uint2 u2 = *(const uint2*)(h1c + (uint32_t)o2);
                uint2 u3 = *(const uint2*)(h1c + (uint32_t)o3);
                a0 += __builtin_amdgcn_cvt_pk_f32_fp8(u0.x, false) * m0;
                a1 += __builtin_amdgcn_cvt_pk_f32_fp8(u0.x, true) * m0;
                a2 += __builtin_amdgcn_cvt_pk_f32_fp8(u0.y, false) * m0;
                a3 += __builtin_amdgcn_cvt_pk_f32_fp8(u0.y, true) * m0;
                a0 += __builtin_amdgcn_cvt_pk_f32_fp8(u1.x, false) * m1;
                a1 += __builtin_amdgcn_cvt_pk_f32_fp8(u1.x, true) * m1;
                a2 += __builtin_amdgcn_cvt_pk_f32_fp8(u1.y, false) * m1;
                a3 += __builtin_amdgcn_cvt_pk_f32_fp8(u1.y, true) * m1;
                a0 += __builtin_amdgcn_cvt_pk_f32_fp8(u2.x, false) * m2;
                a1 += __builtin_amdgcn_cvt_pk_f32_fp8(u2.x, true) * m2;
                a2 += __builtin_amdgcn_cvt_pk_f32_fp8(u2.y, false) * m2;
                a3 += __builtin_amdgcn_cvt_pk_f32_fp8(u2.y, true) * m2;
                a0 += __builtin_amdgcn_cvt_pk_f32_fp8(u3.x, false) * m3;
                a1 += __builtin_amdgcn_cvt_pk_f32_fp8(u3.x, true) * m3;
                a2 += __builtin_amdgcn_cvt_pk_f32_fp8(u3.y, false) * m3;
                a3 += __builtin_amdgcn_cvt_pk_f32_fp8(u3.y, true) * m3;
            }
            i += cnt;
        }
        float ac[8] = {a0.x, a0.y, a1.x, a1.y, a2.x, a2.y, a3.x, a3.y};
        // fold the 4 edge-groups (lane bits 4,5)
#pragma unroll
        for (int j = 0; j < 8; ++j) {
            ac[j] += __shfl_xor(ac[j], 16, 64);
            ac[j] += __shfl_xor(ac[j], 32, 64);
        }
        if (lane < 16) {
            float sc = rs_in[w];
            float f0, f1;
            uint32_t o0, o1, o2, o3;
            f0 = fmaxf(fmaf(ac[0], sc, blo.x), 0.f); f1 = fmaxf(fmaf(ac[1], sc, blo.y), 0.f);
            o0 = (uint32_t)(unsigned short)f2bf(f0) | ((uint32_t)(unsigned short)f2bf(f1) << 16);
            f0 = fmaxf(fmaf(ac[2], sc, blo.z), 0.f); f1 = fmaxf(fmaf(ac[3], sc, blo.w), 0.f);
            o1 = (uint32_t)(unsigned short)f2bf(f0) | ((uint32_t)(unsigned short)f2bf(f1) << 16);
            f0 = fmaxf(fmaf(ac[4], sc, bhi.x), 0.f); f1 = fmaxf(fmaf(ac[5], sc, bhi.y), 0.f);
            o2 = (uint32_t)(unsigned short)f2bf(f0) | ((uint32_t)(unsigned short)f2bf(f1) << 16);
            f0 = fmaxf(fmaf(ac[6], sc, bhi.z), 0.f); f1 = fmaxf(fmaf(ac[7], sc, bhi.w), 0.f);
            o3 = (uint32_t)(unsigned short)f2bf(f0) | ((uint32_t)(unsigned short)f2bf(f1) << 16);
            int woff = (wv * 256 + ql * 16) ^ ((wv & 7) << 4);
            *(uint4*)((char*)x1s + woff) = make_uint4(o0, o1, o2, o3);
        }
    }
    __syncthreads();
    int vr = min(4, N - w_base);
    if (wv < 3) {
        // W2 fragments loaded here (after edge phase) to keep hot-loop VGPR pressure low
        short8 wf0 = *(const short8*)&Wg2[((wv * 4 + 0) * 64 + lane) * 8];
        short8 wf1 = *(const short8*)&Wg2[((wv * 4 + 1) * 64 + lane) * 8];
        short8 wf2 = *(const short8*)&Wg2[((wv * 4 + 2) * 64 + lane) * 8];
        short8 wf3 = *(const short8*)&Wg2[((wv * 4 + 3) * 64 + lane) * 8];
        int row = lane & 15, kc = lane >> 4;
        int rbase = row * 256 + kc * 16;
        int swz = (row & 7) << 4;
        f32x4 c = {};
        c = __builtin_amdgcn_mfma_f32_16x16x32_bf16(*(short8*)((char*)x1s + ((rbase + 0) ^ swz)),   wf0, c, 0, 0, 0);
        c = __builtin_amdgcn_mfma_f32_16x16x32_bf16(*(short8*)((char*)x1s + ((rbase + 64) ^ swz)),  wf1, c, 0, 0, 0);
        c = __builtin_amdgcn_mfma_f32_16x16x32_bf16(*(short8*)((char*)x1s + ((rbase + 128) ^ swz)), wf2, c, 0, 0, 0);
        c = __builtin_amdgcn_mfma_f32_16x16x32_bf16(*(short8*)((char*)x1s + ((rbase + 192) ^ swz)), wf3, c, 0, 0, 0);
        int cc = wv * 16 + row;     // output column 0..47 (only <40 valid)
        if (cc < OUT_DIM && kc == 0) {   // C rows 0..3 live in kc==0 lanes
            float s0 = rs_out[w_base + 0];
            float s1 = (vr > 1) ? rs_out[w_base + 1] : 0.f;
            float s2 = (vr > 2) ? rs_out[w_base + 2] : 0.f;
            float s3 = (vr > 3) ? rs_out[w_base + 3] : 0.f;
            int pk = __builtin_amdgcn_cvt_pk_fp8_f32(c[0] * s0, c[1] * s1, 0, false);
            pk = __builtin_amdgcn_cvt_pk_fp8_f32(c[2] * s2, c[3] * s3, pk, true);
            hs2[cc] = (uint32_t)pk;      // banks 0..15 per wave: conflict-free
        }
    }
    __syncthreads();
    if (t < 64) {                        // assemble padded 64B rows: dword d of row `node`
        int node = t >> 4, d = t & 15;
        uint32_t v = 0;
        if (d < 10) {
            int sh = node * 8;
            uint32_t b0 = (hs2[4 * d + 0] >> sh) & 0xffu;
            uint32_t b1 = (hs2[4 * d + 1] >> sh) & 0xffu;
            uint32_t b2 = (hs2[4 * d + 2] >> sh) & 0xffu;
            uint32_t b3 = (hs2[4 * d + 3] >> sh) & 0xffu;
            v = b0 | (b1 << 8) | (b2 << 16) | (b3 << 24);
        }
        if (node < vr) h2f[(size_t)(w_base + node) * 16 + d] = v;
    }
}

// ---------------- SpMM2 (fp8, 64B-padded rows) + bias + log_softmax ----------------
// 8 lanes/edge x uint2; 32 edges per it-step = 4 independent loads in flight; mask-free hot loop.
__global__ __launch_bounds__(256) void k_spmm2(const char* __restrict__ h2c, const int* __restrict__ rp,
                                               const int* __restrict__ col, const float* __restrict__ rs_in,
                                               const float* __restrict__ b2, float* __restrict__ out, int n) {
    int w = (blockIdx.x * 256 + threadIdx.x) >> 6;
    int lane = threadIdx.x & 63;
    if (w >= n) return;
    int grp = lane >> 3, fl = lane & 7;       // fl: feature-byte group (fl<5 real, 5..7 pad=0)
    int qoff = fl << 3;
    int s = rp[w], e = rp[w + 1];
    f32x2 a0 = {0.f, 0.f}, a1 = {0.f, 0.f}, a2 = {0.f, 0.f}, a3 = {0.f, 0.f};
    int i = s;
    while (i < e) {
        int cnt = min(64, e - i);
        int cl = (lane < cnt) ? lane : cnt - 1;
        int rof = col[i + cl] << 6;           // byte offset of 64B row
        int nfull = cnt & ~31;
        int it = 0;
        for (; it < nfull; it += 32) {        // mask-free full steps
            int o0 = __shfl(rof, it + grp, 64) + qoff;
            int o1 = __shfl(rof, it + 8 + grp, 64) + qoff;
            int o2 = __shfl(rof, it + 16 + grp, 64) + qoff;
            int o3 = __shfl(rof, it + 24 + grp, 64) + qoff;
            uint2 u0 = *(const uint2*)(h2c + (uint32_t)o0);
            uint2 u1 = *(const uint2*)(h2c + (uint32_t)o1);
            uint2 u2 = *(const uint2*)(h2c + (uint32_t)o2);
            uint2 u3 = *(const uint2*)(h2c + (uint32_t)o3);
            a0 += __builtin_amdgcn_cvt_pk_f32_fp8(u0.x, false);
            a1 += __builtin_amdgcn_cvt_pk_f32_fp8(u0.x, true);
            a2 += __builtin_amdgcn_cvt_pk_f32_fp8(u0.y, false);
            a3 += __builtin_amdgcn_cvt_pk_f32_fp8(u0.y, true);
            a0 += __builtin_amdgcn_cvt_pk_f32_fp8(u1.x, false);
            a1 += __builtin_amdgcn_cvt_pk_f32_fp8(u1.x, true);
            a2 += __builtin_amdgcn_cvt_pk_f32_fp8(u1.y, false);
            a3 += __builtin_amdgcn_cvt_pk_f32_fp8(u1.y, true);
            a0 += __builtin_amdgcn_cvt_pk_f32_fp8(u2.x, false);
            a1 += __builtin_amdgcn_cvt_pk_f32_fp8(u2.x, true);
            a2 += __builtin_amdgcn_cvt_pk_f32_fp8(u2.y, false);
            a3 += __builtin_amdgcn_cvt_pk_f32_fp8(u2.y, true);
            a0 += __builtin_amdgcn_cvt_pk_f32_fp8(u3.x, false);
            a1 += __builtin_amdgcn_cvt_pk_f32_fp8(u3.x, true);
            a2 += __builtin_amdgcn_cvt_pk_f32_fp8(u3.y, false);
            a3 += __builtin_amdgcn_cvt_pk_f32_fp8(u3.y, true);
        }
        if (it < cnt) {                       // one masked tail step (<=31 edges)
            int e0 = it + grp;                // e0+24 <= 63 always
            int o0 = __shfl(rof, e0, 64) + qoff;
            int o1 = __shfl(rof, e0 + 8, 64) + qoff;
            int o2 = __shfl(rof, e0 + 16, 64) + qoff;
            int o3 = __shfl(rof, e0 + 24, 64) + qoff;
            float mv0 = (e0 < cnt) ? 1.f : 0.f;
            float mv1 = (e0 + 8 < cnt) ? 1.f : 0.f;
            float mv2 = (e0 + 16 < cnt) ? 1.f : 0.f;
            float mv3 = (e0 + 24 < cnt) ? 1.f : 0.f;
            f32x2 m0 = {mv0, mv0}, m1 = {mv1, mv1}, m2 = {mv2, mv2}, m3 = {mv3, mv3};
            uint2 u0 = *(const uint2*)(h2c + (uint32_t)o0);
            uint2 u1 = *(const uint2*)(h2c + (uint32_t)o1);
            uint2 u2 = *(const uint2*)(h2c + (uint32_t)o2);
            uint2 u3 = *(const uint2*)(h2c + (uint32_t)o3);
            a0 += __builtin_amdgcn_cvt_pk_f32_fp8(u0.x, false) * m0;
            a1 += __builtin_amdgcn_cvt_pk_f32_fp8(u0.x, true) * m0;
            a2 += __builtin_amdgcn_cvt_pk_f32_fp8(u0.y, false) * m0;
            a3 += __builtin_amdgcn_cvt_pk_f32_fp8(u0.y, true) * m0;
            a0 += __builtin_amdgcn_cvt_pk_f32_fp8(u1.x, false) * m1;
            a1 += __builtin_amdgcn_cvt_pk_f32_fp8(u1.x, true) * m1;
            a2 += __builtin_amdgcn_cvt_pk_f32_fp8(u1.y, false) * m1;
            a3 += __builtin_amdgcn_cvt_pk_f32_fp8(u1.y, true) * m1;
            a0 += __builtin_amdgcn_cvt_pk_f32_fp8(u2.x, false) * m2;
            a1 += __builtin_amdgcn_cvt_pk_f32_fp8(u2.x, true) * m2;
            a2 += __builtin_amdgcn_cvt_pk_f32_fp8(u2.y, false) * m2;
            a3 += __builtin_amdgcn_cvt_pk_f32_fp8(u2.y, true) * m2;
            a0 += __builtin_amdgcn_cvt_pk_f32_fp8(u3.x, false) * m3;
            a1 += __builtin_amdgcn_cvt_pk_f32_fp8(u3.x, true) * m3;
            a2 += __builtin_amdgcn_cvt_pk_f32_fp8(u3.y, false) * m3;
            a3 += __builtin_amdgcn_cvt_pk_f32_fp8(u3.y, true) * m3;
        }
        i += cnt;
    }
    float ac[8] = {a0.x, a0.y, a1.x, a1.y, a2.x, a2.y, a3.x, a3.y};
    // fold 8 edge-groups (lane bits 3,4,5)
#pragma unroll
    for (int j = 0; j < 8; ++j) {
        ac[j] += __shfl_xor(ac[j], 8, 64);
        ac[j] += __shfl_xor(ac[j], 16, 64);
        ac[j] += __shfl_xor(ac[j], 32, 64);
    }
    bool act = lane < 5;
    float sc = rs_in[w];
    int bb = (fl < 5) ? fl * 8 : 0;           // guard b2 OOB for pad lanes
    float val[8];
#pragma unroll
    for (int j = 0; j < 8; ++j)
        val[j] = fmaf(ac[j], sc, b2[bb + j]);
    float pm = -INFINITY;
    if (act) {
        pm = val[0];
#pragma unroll
        for (int j = 1; j < 8; ++j) pm = fmaxf(pm, val[j]);
    }
    pm = fmaxf(pm, __shfl_xor(pm, 4, 8));
    pm = fmaxf(pm, __shfl_xor(pm, 2, 8));
    pm = fmaxf(pm, __shfl_xor(pm, 1, 8));
    float ex = 0.f;
    if (act) {
#pragma unroll
        for (int j = 0; j < 8; ++j) ex += expf(val[j] - pm);
    }
    ex += __shfl_xor(ex, 4, 8);
    ex += __shfl_xor(ex, 2, 8);
    ex += __shfl_xor(ex, 1, 8);
    if (act) {
        float l = pm + logf(ex);
        float4 o0 = {val[0] - l, val[1] - l, val[2] - l, val[3] - l};
        float4 o1 = {val[4] - l, val[5] - l, val[6] - l, val[7] - l};
        float* op = out + (size_t)w * OUT_DIM + lane * 8;
        *(float4*)op = o0;
        *(float4*)(op + 4) = o1;
    }
}

// ---------------- launch ----------------

extern "C" void kernel_launch(void* const* d_in, const int* in_sizes, int n_in,
                              void* d_out, int out_size, void* d_ws, size_t ws_size,
                              hipStream_t stream) {
    const int N = in_sizes[0] / IN_DIM;
    const int E = in_sizes[5];
    const float* h  = (const float*)d_in[0];
    const float* W1 = (const float*)d_in[1];
    const float* b1 = (const float*)d_in[2];
    const float* W2 = (const float*)d_in[3];
    const float* b2 = (const float*)d_in[4];
    const int* src  = (const int*)d_in[5];
    const int* dst  = (const int*)d_in[6];
    float* out = (float*)d_out;

    const int NBINS  = (N + BIN_SIZE - 1) >> BIN_SHIFT;   // 98
    const int NCHUNK = (E + CHUNK - 1) / CHUNK;           // 782

    char* w = (char*)d_ws;
    size_t off = 0;
    auto alloc = [&](size_t bytes) -> void* {
        void* p = w + off;
        off += (bytes + 255) & ~(size_t)255;
        return p;
    };
    int* deg_in   = (int*)alloc((size_t)N * 4);
    int* deg_out  = (int*)alloc((size_t)N * 4);
    int* row_ptr  = (int*)alloc((size_t)(N + 1) * 4);
    int* cursor   = (int*)alloc((size_t)N * 4);
    int* bsum     = (int*)alloc(1024 * 4);
    float* rs_out = (float*)alloc((size_t)N * 4);
    float* rs_in  = (float*)alloc((size_t)N * 4);
    int* col      = (int*)alloc((size_t)E * 4);
    int* bboD     = (int*)alloc((size_t)NCHUNK * (NBINS + 1) * 4);
    int* bboS     = (int*)alloc((size_t)NCHUNK * (NBINS + 1) * 4);
    short* Wg     = (short*)alloc((size_t)8 * 8 * 64 * 8 * 2);    // 64 KB
    short* Wg2    = (short*)alloc((size_t)3 * 4 * 64 * 8 * 2);    // 12 KB
    float* b1p    = (float*)alloc((size_t)HID * 4);
    int* hsave    = (int*)alloc((size_t)NBINS * GSPLIT * BIN_SIZE * 4);   // 3.2 MB
    uint32_t* stD = (uint32_t*)alloc((size_t)E * 4);              // 12.8 MB
    unsigned short* stS = (unsigned short*)alloc((size_t)E * 2);  // 6.4 MB
    uint32_t* h1f = (uint32_t*)alloc((size_t)N * HID);            // fp8 [N][128], 12.8 MB (own buffer: col+gemm1 overlap)
    uint32_t* h2f = (uint32_t*)alloc((size_t)N * 64);             // fp8 [N][64] (40 real + 24 pad), 6.4 MB

    int gN = (N + 255) / 256;
    int NB = (N + 1023) / 1024;
    int Z = (N + 3) / 4;
    int setup_units = 8192 + 3 * 4 * 64 * 8 + HID + 2 * Z;
    int setupBlocks = (setup_units + 255) / 256;
    int colBlocks = ((NBINS + 7) / 8 * 8) * GSPLIT;   // XCD-affine padded (b%8 == blockIdx%8)

    k_init<<<setupBlocks + NCHUNK, 256, 0, stream>>>(W1, W2, b1, Wg, Wg2, b1p, deg_in, deg_out, Z,
                                                     src, dst, stD, stS, bboD, bboS, E, NBINS, setupBlocks);
    k_deg<<<dim3(NBINS, GSPLIT, 2), 256, 0, stream>>>(stD, bboD, stS, bboS, deg_in, deg_out, hsave, NCHUNK, NBINS);
    k_scan1<<<NB, 256, 0, stream>>>(deg_in, row_ptr, bsum, rs_in, N);
    k_scan3<<<gN, 256, 0, stream>>>(row_ptr, bsum, cursor, deg_out, rs_out, N, E, NB);
    k_colgemm1<<<colBlocks + (N + 63) / 64, 256, 0, stream>>>(stD, bboD, hsave, cursor, col, NCHUNK, NBINS,
                                                              colBlocks, h, Wg, rs_out, h1f, N);
    k_spmm1f<<<(N + 3) / 4, 256, 0, stream>>>((const char*)h1f, row_ptr, col, rs_in, rs_out, b1p, Wg2, h2f, N);
    k_spmm2<<<(N + 3) / 4, 256, 0, stream>>>((const char*)h2f, row_ptr, col, rs_in, b2, out, N);
}